// Round 2
// baseline (2442.459 us; speedup 1.0000x reference)
//
#include <hip/hip_runtime.h>

#define BATCH  16
#define SEQ    4096
#define DIM    64
#define NHASH  8
#define NCHUNK 512   // chunks per batch row (NHASH * SEQ / 64)
#define LSTR   68    // LDS row stride in floats: 68*4=272 B, 16B-aligned,
                     // rotates banks by 4 per row -> conflict-free patterns

// ---------------------------------------------------------------------------
// Kernel 1: LSH hashing. One thread per (b,t) token. rotations are read with
// wave-uniform indices -> scalar loads through sL1. Per-thread q row lives in
// a private LDS column (dynamic f-indexing without VGPR-array spills).
// buckets[(b*8+h)*4096 + t] = argmax over [r, -r] (first-max wins, like jnp).
// ---------------------------------------------------------------------------
__global__ __launch_bounds__(256) void lsh_hash_kernel(
    const float* __restrict__ qk, const float* __restrict__ rot,
    int* __restrict__ buckets)
{
    __shared__ float qs[256 * DIM];
    int tid = threadIdx.x;
    int gid = blockIdx.x * 256 + tid;      // b*4096 + t
    int b = gid >> 12, t = gid & 4095;

    const float4* src = (const float4*)(qk + (size_t)gid * DIM);
#pragma unroll
    for (int u = 0; u < 16; ++u) {
        float4 x = src[u];
        qs[(4*u + 0) * 256 + tid] = x.x;
        qs[(4*u + 1) * 256 + tid] = x.y;
        qs[(4*u + 2) * 256 + tid] = x.z;
        qs[(4*u + 3) * 256 + tid] = x.w;
    }
    // no __syncthreads needed: each thread reads only its own column

    for (int h = 0; h < NHASH; ++h) {
        float acc[32];
#pragma unroll
        for (int i = 0; i < 32; ++i) acc[i] = 0.f;
        for (int f = 0; f < DIM; ++f) {
            float qf = qs[f * 256 + tid];
            const float* rp = rot + (f * NHASH + h) * 32;   // wave-uniform addr
#pragma unroll
            for (int i = 0; i < 32; ++i) acc[i] = fmaf(qf, rp[i], acc[i]);
        }
        float best = acc[0]; int bi = 0;
#pragma unroll
        for (int i = 1; i < 32; ++i) { if (acc[i] > best) { best = acc[i]; bi = i; } }
#pragma unroll
        for (int i = 0; i < 32; ++i) { float nv = -acc[i]; if (nv > best) { best = nv; bi = i + 32; } }
        buckets[((size_t)b * NHASH + h) * SEQ + t] = bi;
    }
}

// ---------------------------------------------------------------------------
// Kernel 2: stable counting sort per (b,h). One wave per block. Lane l owns
// tokens [64l, 64l+64) (contiguous -> stability). hist[lane][bucket] local
// histograms, column prefix over lanes by lane==bucket, then ordered scatter.
// st[(b*8+h)*4096 + pos] = original token t, sorted by (bucket, t).
// ---------------------------------------------------------------------------
__global__ __launch_bounds__(64) void lsh_sort_kernel(
    const int* __restrict__ buckets, int* __restrict__ st)
{
    int bh = blockIdx.x;                 // b*8 + h
    int lane = threadIdx.x;              // 0..63
    const int* bp = buckets + (size_t)bh * SEQ;
    __shared__ int hist[64 * 64];        // [lane][bucket]
    __shared__ int tot[64];
    __shared__ int base[64];

    for (int i = 0; i < 64; ++i) hist[(lane << 6) + i] = 0;
    __syncthreads();
    for (int u = 0; u < 64; ++u) {
        int tt = (lane << 6) + u;
        hist[(lane << 6) + bp[tt]] += 1;     // private region, no race
    }
    __syncthreads();
    {   // lane == bucket: exclusive prefix over lanes, total per bucket
        int run = 0;
        for (int l = 0; l < 64; ++l) {
            int idx = (l << 6) + lane;
            int c0 = hist[idx];
            hist[idx] = run;
            run += c0;
        }
        tot[lane] = run;
    }
    __syncthreads();
    if (lane == 0) {
        int r = 0;
        for (int i = 0; i < 64; ++i) { base[i] = r; r += tot[i]; }
    }
    __syncthreads();
    int* op = st + (size_t)bh * SEQ;
    for (int u = 0; u < 64; ++u) {
        int tt = (lane << 6) + u;
        int bb = bp[tt];
        int idx = (lane << 6) + bb;
        int pos = base[bb] + hist[idx];
        hist[idx] = pos - base[bb] + 1;
        op[pos] = tt;
    }
}

// ---------------------------------------------------------------------------
// Kernel 3: chunked attention. Block = one (b, chunk). Keys processed in two
// 64-row halves: own chunk, then look-back chunk (c-1 mod 512). Accumulates
// numerator N[b][t][d] += sum_j exp(dots)*v and denominator D[b][t] += sum_j
// exp(dots) with global fp32 atomics (the logsumexp combine collapses to N/D).
// LDS tiles padded to LSTR=68 floats/row: bank = (4*row + col) % 32, which
// makes every access pattern below <=2-way (free per m136).
// ---------------------------------------------------------------------------
__global__ __launch_bounds__(256, 2) void lsh_attn_kernel(
    const float* __restrict__ qk, const float* __restrict__ v,
    const int* __restrict__ st, float* __restrict__ Nbuf, float* __restrict__ Dbuf)
{
    __shared__ float Qs[64 * LSTR];
    __shared__ float Ks[64 * LSTR];
    __shared__ float Vs[64 * LSTR];
    __shared__ float Ps[64 * LSTR];
    __shared__ int   tq[64];
    __shared__ int   tk[64];
    __shared__ float Drow[64];

    int tid = threadIdx.x;
    int bc = blockIdx.x;
    int b = bc >> 9, c = bc & (NCHUNK - 1);
    int cm = (c + NCHUNK - 1) & (NCHUNK - 1);

    const int*   stb = st + (size_t)b * (NHASH * SEQ);
    const float* qkb = qk + (size_t)b * SEQ * DIM;
    const float* vb  = v  + (size_t)b * SEQ * DIM;

    if (tid < 64) { tq[tid] = stb[c * 64 + tid]; Drow[tid] = 0.f; }
    __syncthreads();

    {   // load Q (unnormalized): 4 threads/row, 16 floats each
        int r = tid >> 2, s = tid & 3;
        const float4* s4 = (const float4*)(qkb + (size_t)tq[r] * DIM + s * 16);
        float4* d4 = (float4*)(Qs + r * LSTR + s * 16);
        d4[0] = s4[0]; d4[1] = s4[1]; d4[2] = s4[2]; d4[3] = s4[3];
    }

    int ty = tid >> 4, tx = tid & 15;    // ty in 0..15, tx in 0..15
    float acc[4][4];
#pragma unroll
    for (int a = 0; a < 4; ++a)
        acc[a][0] = acc[a][1] = acc[a][2] = acc[a][3] = 0.f;

    for (int half = 0; half < 2; ++half) {
        int ck = half ? cm : c;
        __syncthreads();                       // Q ready / prev-half consumers done
        if (tid < 64) tk[tid] = stb[ck * 64 + tid];
        __syncthreads();                       // tk visible
        {   // load K (L2-normalized) and V: 4 threads/row, 16 floats each
            int r = tid >> 2, s = tid & 3;
            int trow = tk[r];
            const float4* k4 = (const float4*)(qkb + (size_t)trow * DIM + s * 16);
            float4 a0 = k4[0], a1 = k4[1], a2 = k4[2], a3 = k4[3];
            float ss = a0.x*a0.x + a0.y*a0.y + a0.z*a0.z + a0.w*a0.w
                     + a1.x*a1.x + a1.y*a1.y + a1.z*a1.z + a1.w*a1.w
                     + a2.x*a2.x + a2.y*a2.y + a2.z*a2.z + a2.w*a2.w
                     + a3.x*a3.x + a3.y*a3.y + a3.z*a3.z + a3.w*a3.w;
            ss += __shfl_xor(ss, 1);
            ss += __shfl_xor(ss, 2);
            float sc = 1.0f / fmaxf(sqrtf(ss), 1e-12f);
            float4* kd = (float4*)(Ks + r * LSTR + s * 16);
            a0.x *= sc; a0.y *= sc; a0.z *= sc; a0.w *= sc;
            a1.x *= sc; a1.y *= sc; a1.z *= sc; a1.w *= sc;
            a2.x *= sc; a2.y *= sc; a2.z *= sc; a2.w *= sc;
            a3.x *= sc; a3.y *= sc; a3.z *= sc; a3.w *= sc;
            kd[0] = a0; kd[1] = a1; kd[2] = a2; kd[3] = a3;
            const float4* v4 = (const float4*)(vb + (size_t)trow * DIM + s * 16);
            float4* vd = (float4*)(Vs + r * LSTR + s * 16);
            vd[0] = v4[0]; vd[1] = v4[1]; vd[2] = v4[2]; vd[3] = v4[3];
        }
        __syncthreads();                       // K/V staged
        {   // dots: thread tile i = ty+16a (4 rows) x j = tx+16jj (4 cols)
            float dt[4][4];
#pragma unroll
            for (int a = 0; a < 4; ++a)
                dt[a][0] = dt[a][1] = dt[a][2] = dt[a][3] = 0.f;
            for (int k = 0; k < 64; k += 4) {
                float4 qv[4], kv[4];
#pragma unroll
                for (int a = 0; a < 4; ++a)
                    qv[a] = *(const float4*)(Qs + (ty + 16*a) * LSTR + k);
#pragma unroll
                for (int jj = 0; jj < 4; ++jj)
                    kv[jj] = *(const float4*)(Ks + (tx + 16*jj) * LSTR + k);
#pragma unroll
                for (int a = 0; a < 4; ++a) {
                    const float* qa = (const float*)&qv[a];
#pragma unroll
                    for (int jj = 0; jj < 4; ++jj) {
                        const float* kj = (const float*)&kv[jj];
                        dt[a][jj] = fmaf(qa[0], kj[0],
                                    fmaf(qa[1], kj[1],
                                    fmaf(qa[2], kj[2],
                                    fmaf(qa[3], kj[3], dt[a][jj]))));
                    }
                }
            }
            // mask self-attention, exp, write P (scalar, conflict-free),
            // shuffle-reduce row sums across the 16 tx lanes, single writer
#pragma unroll
            for (int a = 0; a < 4; ++a) {
                int i = ty + 16*a;
                int ti = tq[i];
                float rs = 0.f;
#pragma unroll
                for (int jj = 0; jj < 4; ++jj) {
                    int j = tx + 16*jj;
                    float p = (ti == tk[j]) ? 0.f : __expf(dt[a][jj] * 0.125f);
                    Ps[i * LSTR + j] = p;
                    rs += p;
                }
                rs += __shfl_xor(rs, 1);
                rs += __shfl_xor(rs, 2);
                rs += __shfl_xor(rs, 4);
                rs += __shfl_xor(rs, 8);
                if (tx == 0) Drow[i] += rs;   // unique owner (ty,a) -> row i
            }
        }
        __syncthreads();                       // P staged
        {   // PV accumulate: thread tile i = ty+16a x d = 4tx..4tx+3
            for (int j = 0; j < 64; j += 4) {
                float4 pr[4], vr[4];
#pragma unroll
                for (int a = 0; a < 4; ++a)
                    pr[a] = *(const float4*)(Ps + (ty + 16*a) * LSTR + j);
#pragma unroll
                for (int jj = 0; jj < 4; ++jj)
                    vr[jj] = *(const float4*)(Vs + (j + jj) * LSTR + 4*tx);
#pragma unroll
                for (int a = 0; a < 4; ++a) {
                    const float* pa = (const float*)&pr[a];
#pragma unroll
                    for (int jj = 0; jj < 4; ++jj) {
                        const float* vj = (const float*)&vr[jj];
                        float p = pa[jj];
                        acc[a][0] = fmaf(p, vj[0], acc[a][0]);
                        acc[a][1] = fmaf(p, vj[1], acc[a][1]);
                        acc[a][2] = fmaf(p, vj[2], acc[a][2]);
                        acc[a][3] = fmaf(p, vj[3], acc[a][3]);
                    }
                }
            }
        }
    }
    __syncthreads();
    {   // scatter-accumulate into global N / D
#pragma unroll
        for (int a = 0; a < 4; ++a) {
            int i = ty + 16*a;
            int t = tq[i];
            float* np = Nbuf + ((size_t)b * SEQ + t) * DIM + 4*tx;
            atomicAdd(np + 0, acc[a][0]);
            atomicAdd(np + 1, acc[a][1]);
            atomicAdd(np + 2, acc[a][2]);
            atomicAdd(np + 3, acc[a][3]);
        }
        if (tid < 64) atomicAdd(&Dbuf[(size_t)b * SEQ + tq[tid]], Drow[tid]);
    }
}

// ---------------------------------------------------------------------------
// Kernel 4: out = N / D  (one float4 per thread)
// ---------------------------------------------------------------------------
__global__ __launch_bounds__(256) void lsh_combine_kernel(
    const float* __restrict__ Nbuf, const float* __restrict__ Dbuf,
    float* __restrict__ out)
{
    int gid = blockIdx.x * 256 + threadIdx.x;   // float4 index
    float4 n = ((const float4*)Nbuf)[gid];
    float d = Dbuf[gid >> 4];                   // 16 float4 per token
    float inv = 1.0f / d;
    float4 o;
    o.x = n.x * inv; o.y = n.y * inv; o.z = n.z * inv; o.w = n.w * inv;
    ((float4*)out)[gid] = o;
}

extern "C" void kernel_launch(void* const* d_in, const int* in_sizes, int n_in,
                              void* d_out, int out_size, void* d_ws, size_t ws_size,
                              hipStream_t stream)
{
    const float* qk  = (const float*)d_in[0];
    const float* v   = (const float*)d_in[1];
    const float* rot = (const float*)d_in[2];
    float* out = (float*)d_out;

    char* w = (char*)d_ws;
    // workspace layout (21.3 MB total):
    //   [0, 2MB)      buckets  : int[16*8*4096]
    //   [2MB, 4MB)    st       : int[16*8*4096]
    //   [4MB, 20MB)   Nbuf     : float[16*4096*64]
    //   [20MB, +256K) Dbuf     : float[16*4096]
    int*   buckets = (int*)(w);
    int*   st      = (int*)(w + 2097152);
    float* Nbuf    = (float*)(w + 4194304);
    float* Dbuf    = (float*)(w + 4194304 + 16777216);

    hipMemsetAsync(w + 4194304, 0, 16777216 + 262144, stream);
    lsh_hash_kernel<<<256, 256, 0, stream>>>(qk, rot, buckets);
    lsh_sort_kernel<<<128, 64, 0, stream>>>(buckets, st);
    lsh_attn_kernel<<<8192, 256, 0, stream>>>(qk, v, st, Nbuf, Dbuf);
    lsh_combine_kernel<<<4096, 256, 0, stream>>>(Nbuf, Dbuf, out);
}

// Round 3
// 734.981 us; speedup vs baseline: 3.3232x; 3.3232x over previous
//
#include <hip/hip_runtime.h>

#define BATCH  16
#define SEQ    4096
#define DIM    64
#define NHASH  8
#define NCHUNK 512   // chunks per batch row (NHASH * SEQ / 64)
#define LSTR   68    // LDS row stride in floats: 68*4=272 B, 16B-aligned,
                     // rotates banks by 4 per row -> conflict-free patterns

// ---------------------------------------------------------------------------
// Kernel 1: LSH hashing. One thread per (b,t) token. rotations are read with
// wave-uniform indices -> scalar loads through sL1. Per-thread q row lives in
// a private LDS column (dynamic f-indexing without VGPR-array spills).
// buckets[(b*8+h)*4096 + t] = argmax over [r, -r] (first-max wins, like jnp).
// ---------------------------------------------------------------------------
__global__ __launch_bounds__(256) void lsh_hash_kernel(
    const float* __restrict__ qk, const float* __restrict__ rot,
    int* __restrict__ buckets)
{
    __shared__ float qs[256 * DIM];
    int tid = threadIdx.x;
    int gid = blockIdx.x * 256 + tid;      // b*4096 + t
    int b = gid >> 12, t = gid & 4095;

    const float4* src = (const float4*)(qk + (size_t)gid * DIM);
#pragma unroll
    for (int u = 0; u < 16; ++u) {
        float4 x = src[u];
        qs[(4*u + 0) * 256 + tid] = x.x;
        qs[(4*u + 1) * 256 + tid] = x.y;
        qs[(4*u + 2) * 256 + tid] = x.z;
        qs[(4*u + 3) * 256 + tid] = x.w;
    }
    // no __syncthreads needed: each thread reads only its own column

    for (int h = 0; h < NHASH; ++h) {
        float acc[32];
#pragma unroll
        for (int i = 0; i < 32; ++i) acc[i] = 0.f;
        for (int f = 0; f < DIM; ++f) {
            float qf = qs[f * 256 + tid];
            const float* rp = rot + (f * NHASH + h) * 32;   // wave-uniform addr
#pragma unroll
            for (int i = 0; i < 32; ++i) acc[i] = fmaf(qf, rp[i], acc[i]);
        }
        float best = acc[0]; int bi = 0;
#pragma unroll
        for (int i = 1; i < 32; ++i) { if (acc[i] > best) { best = acc[i]; bi = i; } }
#pragma unroll
        for (int i = 0; i < 32; ++i) { float nv = -acc[i]; if (nv > best) { best = nv; bi = i + 32; } }
        buckets[((size_t)b * NHASH + h) * SEQ + t] = bi;
    }
}

// ---------------------------------------------------------------------------
// Kernel 2: stable counting sort per (b,h). One wave per block. Lane l owns
// tokens [64l, 64l+64) (contiguous -> stability). hist[lane][bucket] local
// histograms, column prefix over lanes by lane==bucket, then ordered scatter.
// st[(b*8+h)*4096 + pos] = original token t, sorted by (bucket, t).
// ---------------------------------------------------------------------------
__global__ __launch_bounds__(64) void lsh_sort_kernel(
    const int* __restrict__ buckets, int* __restrict__ st)
{
    int bh = blockIdx.x;                 // b*8 + h
    int lane = threadIdx.x;              // 0..63
    const int* bp = buckets + (size_t)bh * SEQ;
    __shared__ int hist[64 * 64];        // [lane][bucket]
    __shared__ int tot[64];
    __shared__ int base[64];

    for (int i = 0; i < 64; ++i) hist[(lane << 6) + i] = 0;
    __syncthreads();
    for (int u = 0; u < 64; ++u) {
        int tt = (lane << 6) + u;
        hist[(lane << 6) + bp[tt]] += 1;     // private region, no race
    }
    __syncthreads();
    {   // lane == bucket: exclusive prefix over lanes, total per bucket
        int run = 0;
        for (int l = 0; l < 64; ++l) {
            int idx = (l << 6) + lane;
            int c0 = hist[idx];
            hist[idx] = run;
            run += c0;
        }
        tot[lane] = run;
    }
    __syncthreads();
    if (lane == 0) {
        int r = 0;
        for (int i = 0; i < 64; ++i) { base[i] = r; r += tot[i]; }
    }
    __syncthreads();
    int* op = st + (size_t)bh * SEQ;
    for (int u = 0; u < 64; ++u) {
        int tt = (lane << 6) + u;
        int bb = bp[tt];
        int idx = (lane << 6) + bb;
        int pos = base[bb] + hist[idx];
        hist[idx] = pos - base[bb] + 1;
        op[pos] = tt;
    }
}

// ---------------------------------------------------------------------------
// Kernel 3: chunked attention. Block = one (b, chunk). Keys processed in two
// 64-row halves: own chunk, then look-back chunk (c-1 mod 512). Accumulates
// numerator N[b][t][d] += sum_j exp(dots)*v and denominator D[b][t] += sum_j
// exp(dots) with global fp32 atomics (the logsumexp combine collapses to N/D).
// LDS tiles padded to LSTR=68; j-tile mapping j = tx+16jj keeps every LDS
// pattern <=2-way (verified R2: conflicts 3.0e8 -> 7.3e6). Hot loops keep
// live ranges small (one qa/pr float4 at a time, unroll 2) to avoid the R2
// scratch-spill regression (VGPR 128 + 7.5 GB of spill HBM traffic).
// ---------------------------------------------------------------------------
__global__ __launch_bounds__(256, 2) void lsh_attn_kernel(
    const float* __restrict__ qk, const float* __restrict__ v,
    const int* __restrict__ st, float* __restrict__ Nbuf, float* __restrict__ Dbuf)
{
    __shared__ float Qs[64 * LSTR];
    __shared__ float Ks[64 * LSTR];
    __shared__ float Vs[64 * LSTR];
    __shared__ float Ps[64 * LSTR];
    __shared__ int   tq[64];
    __shared__ int   tk[64];
    __shared__ float Drow[64];

    int tid = threadIdx.x;
    int bc = blockIdx.x;
    int b = bc >> 9, c = bc & (NCHUNK - 1);
    int cm = (c + NCHUNK - 1) & (NCHUNK - 1);

    const int*   stb = st + (size_t)b * (NHASH * SEQ);
    const float* qkb = qk + (size_t)b * SEQ * DIM;
    const float* vb  = v  + (size_t)b * SEQ * DIM;

    if (tid < 64) { tq[tid] = stb[c * 64 + tid]; Drow[tid] = 0.f; }
    __syncthreads();

    {   // load Q (unnormalized): 4 threads/row, 16 floats each
        int r = tid >> 2, s = tid & 3;
        const float4* s4 = (const float4*)(qkb + (size_t)tq[r] * DIM + s * 16);
        float4* d4 = (float4*)(Qs + r * LSTR + s * 16);
        d4[0] = s4[0]; d4[1] = s4[1]; d4[2] = s4[2]; d4[3] = s4[3];
    }

    int ty = tid >> 4, tx = tid & 15;    // ty in 0..15, tx in 0..15
    float acc[4][4];
#pragma unroll
    for (int a = 0; a < 4; ++a)
        acc[a][0] = acc[a][1] = acc[a][2] = acc[a][3] = 0.f;

    for (int half = 0; half < 2; ++half) {
        int ck = half ? cm : c;
        __syncthreads();                       // Q ready / prev-half consumers done
        if (tid < 64) tk[tid] = stb[ck * 64 + tid];
        __syncthreads();                       // tk visible
        {   // load K (L2-normalized) and V: 4 threads/row, 16 floats each
            int r = tid >> 2, s = tid & 3;
            int trow = tk[r];
            const float4* k4 = (const float4*)(qkb + (size_t)trow * DIM + s * 16);
            float4 a0 = k4[0], a1 = k4[1], a2 = k4[2], a3 = k4[3];
            float ss = a0.x*a0.x + a0.y*a0.y + a0.z*a0.z + a0.w*a0.w
                     + a1.x*a1.x + a1.y*a1.y + a1.z*a1.z + a1.w*a1.w
                     + a2.x*a2.x + a2.y*a2.y + a2.z*a2.z + a2.w*a2.w
                     + a3.x*a3.x + a3.y*a3.y + a3.z*a3.z + a3.w*a3.w;
            ss += __shfl_xor(ss, 1);
            ss += __shfl_xor(ss, 2);
            float sc = 1.0f / fmaxf(sqrtf(ss), 1e-12f);
            float4* kd = (float4*)(Ks + r * LSTR + s * 16);
            a0.x *= sc; a0.y *= sc; a0.z *= sc; a0.w *= sc;
            a1.x *= sc; a1.y *= sc; a1.z *= sc; a1.w *= sc;
            a2.x *= sc; a2.y *= sc; a2.z *= sc; a2.w *= sc;
            a3.x *= sc; a3.y *= sc; a3.z *= sc; a3.w *= sc;
            kd[0] = a0; kd[1] = a1; kd[2] = a2; kd[3] = a3;
            const float4* v4 = (const float4*)(vb + (size_t)trow * DIM + s * 16);
            float4* vd = (float4*)(Vs + r * LSTR + s * 16);
            vd[0] = v4[0]; vd[1] = v4[1]; vd[2] = v4[2]; vd[3] = v4[3];
        }
        __syncthreads();                       // K/V staged
        {   // dots: thread tile i = ty+16a (4 rows) x j = tx+16jj (4 cols)
            float dt[4][4];
#pragma unroll
            for (int a = 0; a < 4; ++a)
                dt[a][0] = dt[a][1] = dt[a][2] = dt[a][3] = 0.f;
#pragma unroll 2
            for (int k = 0; k < 64; k += 4) {
                float4 kv[4];
#pragma unroll
                for (int jj = 0; jj < 4; ++jj)
                    kv[jj] = *(const float4*)(Ks + (tx + 16*jj) * LSTR + k);
#pragma unroll
                for (int a = 0; a < 4; ++a) {
                    float4 qa4 = *(const float4*)(Qs + (ty + 16*a) * LSTR + k);
                    const float* qa = (const float*)&qa4;
#pragma unroll
                    for (int jj = 0; jj < 4; ++jj) {
                        const float* kj = (const float*)&kv[jj];
                        dt[a][jj] = fmaf(qa[0], kj[0],
                                    fmaf(qa[1], kj[1],
                                    fmaf(qa[2], kj[2],
                                    fmaf(qa[3], kj[3], dt[a][jj]))));
                    }
                }
            }
            // mask self-attention, exp, write P (scalar, conflict-free),
            // shuffle-reduce row sums across the 16 tx lanes, single writer
#pragma unroll
            for (int a = 0; a < 4; ++a) {
                int i = ty + 16*a;
                int ti = tq[i];
                float rs = 0.f;
#pragma unroll
                for (int jj = 0; jj < 4; ++jj) {
                    int j = tx + 16*jj;
                    float p = (ti == tk[j]) ? 0.f : __expf(dt[a][jj] * 0.125f);
                    Ps[i * LSTR + j] = p;
                    rs += p;
                }
                rs += __shfl_xor(rs, 1);
                rs += __shfl_xor(rs, 2);
                rs += __shfl_xor(rs, 4);
                rs += __shfl_xor(rs, 8);
                if (tx == 0) Drow[i] += rs;   // unique owner (ty,a) -> row i
            }
        }
        __syncthreads();                       // P staged
        {   // PV accumulate: thread tile i = ty+16a x d = 4tx..4tx+3
#pragma unroll 2
            for (int j = 0; j < 64; j += 4) {
                float4 vr[4];
#pragma unroll
                for (int jj = 0; jj < 4; ++jj)
                    vr[jj] = *(const float4*)(Vs + (j + jj) * LSTR + 4*tx);
#pragma unroll
                for (int a = 0; a < 4; ++a) {
                    float4 pr4 = *(const float4*)(Ps + (ty + 16*a) * LSTR + j);
                    const float* pa = (const float*)&pr4;
#pragma unroll
                    for (int jj = 0; jj < 4; ++jj) {
                        const float* vj = (const float*)&vr[jj];
                        float p = pa[jj];
                        acc[a][0] = fmaf(p, vj[0], acc[a][0]);
                        acc[a][1] = fmaf(p, vj[1], acc[a][1]);
                        acc[a][2] = fmaf(p, vj[2], acc[a][2]);
                        acc[a][3] = fmaf(p, vj[3], acc[a][3]);
                    }
                }
            }
        }
    }
    __syncthreads();
    {   // scatter-accumulate into global N / D
#pragma unroll
        for (int a = 0; a < 4; ++a) {
            int i = ty + 16*a;
            int t = tq[i];
            float* np = Nbuf + ((size_t)b * SEQ + t) * DIM + 4*tx;
            atomicAdd(np + 0, acc[a][0]);
            atomicAdd(np + 1, acc[a][1]);
            atomicAdd(np + 2, acc[a][2]);
            atomicAdd(np + 3, acc[a][3]);
        }
        if (tid < 64) atomicAdd(&Dbuf[(size_t)b * SEQ + tq[tid]], Drow[tid]);
    }
}

// ---------------------------------------------------------------------------
// Kernel 4: out = N / D  (one float4 per thread)
// ---------------------------------------------------------------------------
__global__ __launch_bounds__(256) void lsh_combine_kernel(
    const float* __restrict__ Nbuf, const float* __restrict__ Dbuf,
    float* __restrict__ out)
{
    int gid = blockIdx.x * 256 + threadIdx.x;   // float4 index
    float4 n = ((const float4*)Nbuf)[gid];
    float d = Dbuf[gid >> 4];                   // 16 float4 per token
    float inv = 1.0f / d;
    float4 o;
    o.x = n.x * inv; o.y = n.y * inv; o.z = n.z * inv; o.w = n.w * inv;
    ((float4*)out)[gid] = o;
}

extern "C" void kernel_launch(void* const* d_in, const int* in_sizes, int n_in,
                              void* d_out, int out_size, void* d_ws, size_t ws_size,
                              hipStream_t stream)
{
    const float* qk  = (const float*)d_in[0];
    const float* v   = (const float*)d_in[1];
    const float* rot = (const float*)d_in[2];
    float* out = (float*)d_out;

    char* w = (char*)d_ws;
    // workspace layout (21.3 MB total):
    //   [0, 2MB)      buckets  : int[16*8*4096]
    //   [2MB, 4MB)    st       : int[16*8*4096]
    //   [4MB, 20MB)   Nbuf     : float[16*4096*64]
    //   [20MB, +256K) Dbuf     : float[16*4096]
    int*   buckets = (int*)(w);
    int*   st      = (int*)(w + 2097152);
    float* Nbuf    = (float*)(w + 4194304);
    float* Dbuf    = (float*)(w + 4194304 + 16777216);

    hipMemsetAsync(w + 4194304, 0, 16777216 + 262144, stream);
    lsh_hash_kernel<<<256, 256, 0, stream>>>(qk, rot, buckets);
    lsh_sort_kernel<<<128, 64, 0, stream>>>(buckets, st);
    lsh_attn_kernel<<<8192, 256, 0, stream>>>(qk, v, st, Nbuf, Dbuf);
    lsh_combine_kernel<<<4096, 256, 0, stream>>>(Nbuf, Dbuf, out);
}

// Round 4
// 669.417 us; speedup vs baseline: 3.6486x; 1.0979x over previous
//
#include <hip/hip_runtime.h>

#define BATCH  16
#define SEQ    4096
#define DIM    64
#define NHASH  8
#define NCHUNK 512   // chunks per batch row (NHASH * SEQ / 64)
#define LSTR   68    // LDS row stride in floats: 68*4=272 B, 16B-aligned,
                     // rotates banks by 4 per row -> conflict-free patterns

// ---------------------------------------------------------------------------
// Kernel 1: LSH hashing. One thread per (b,t) token. rotations are read with
// wave-uniform indices -> scalar loads through sL1. Per-thread q row lives in
// a private LDS column (dynamic f-indexing without VGPR-array spills).
// buckets[(b*8+h)*4096 + t] = argmax over [r, -r] (first-max wins, like jnp).
// ---------------------------------------------------------------------------
__global__ __launch_bounds__(256) void lsh_hash_kernel(
    const float* __restrict__ qk, const float* __restrict__ rot,
    int* __restrict__ buckets)
{
    __shared__ float qs[256 * DIM];
    int tid = threadIdx.x;
    int gid = blockIdx.x * 256 + tid;      // b*4096 + t
    int b = gid >> 12, t = gid & 4095;

    const float4* src = (const float4*)(qk + (size_t)gid * DIM);
#pragma unroll
    for (int u = 0; u < 16; ++u) {
        float4 x = src[u];
        qs[(4*u + 0) * 256 + tid] = x.x;
        qs[(4*u + 1) * 256 + tid] = x.y;
        qs[(4*u + 2) * 256 + tid] = x.z;
        qs[(4*u + 3) * 256 + tid] = x.w;
    }
    // no __syncthreads needed: each thread reads only its own column

    for (int h = 0; h < NHASH; ++h) {
        float acc[32];
#pragma unroll
        for (int i = 0; i < 32; ++i) acc[i] = 0.f;
        for (int f = 0; f < DIM; ++f) {
            float qf = qs[f * 256 + tid];
            const float* rp = rot + (f * NHASH + h) * 32;   // wave-uniform addr
#pragma unroll
            for (int i = 0; i < 32; ++i) acc[i] = fmaf(qf, rp[i], acc[i]);
        }
        float best = acc[0]; int bi = 0;
#pragma unroll
        for (int i = 1; i < 32; ++i) { if (acc[i] > best) { best = acc[i]; bi = i; } }
#pragma unroll
        for (int i = 0; i < 32; ++i) { float nv = -acc[i]; if (nv > best) { best = nv; bi = i + 32; } }
        buckets[((size_t)b * NHASH + h) * SEQ + t] = bi;
    }
}

// ---------------------------------------------------------------------------
// Kernel 2: stable counting sort per (b,h). One wave per block. Lane l owns
// tokens [64l, 64l+64) (contiguous -> stability). hist[lane][bucket] local
// histograms, column prefix over lanes by lane==bucket, then ordered scatter.
// st[(b*8+h)*4096 + pos] = original token t, sorted by (bucket, t).
// ---------------------------------------------------------------------------
__global__ __launch_bounds__(64) void lsh_sort_kernel(
    const int* __restrict__ buckets, int* __restrict__ st)
{
    int bh = blockIdx.x;                 // b*8 + h
    int lane = threadIdx.x;              // 0..63
    const int* bp = buckets + (size_t)bh * SEQ;
    __shared__ int hist[64 * 64];        // [lane][bucket]
    __shared__ int tot[64];
    __shared__ int base[64];

    for (int i = 0; i < 64; ++i) hist[(lane << 6) + i] = 0;
    __syncthreads();
    for (int u = 0; u < 64; ++u) {
        int tt = (lane << 6) + u;
        hist[(lane << 6) + bp[tt]] += 1;     // private region, no race
    }
    __syncthreads();
    {   // lane == bucket: exclusive prefix over lanes, total per bucket
        int run = 0;
        for (int l = 0; l < 64; ++l) {
            int idx = (l << 6) + lane;
            int c0 = hist[idx];
            hist[idx] = run;
            run += c0;
        }
        tot[lane] = run;
    }
    __syncthreads();
    if (lane == 0) {
        int r = 0;
        for (int i = 0; i < 64; ++i) { base[i] = r; r += tot[i]; }
    }
    __syncthreads();
    int* op = st + (size_t)bh * SEQ;
    for (int u = 0; u < 64; ++u) {
        int tt = (lane << 6) + u;
        int bb = bp[tt];
        int idx = (lane << 6) + bb;
        int pos = base[bb] + hist[idx];
        hist[idx] = pos - base[bb] + 1;
        op[pos] = tt;
    }
}

// ---------------------------------------------------------------------------
// Kernel 3: chunked attention. Block = one (b, chunk). Keys processed in two
// 64-row halves: own chunk, then look-back chunk (c-1 mod 512). Accumulates
// numerator N[b][t][d] += sum_j exp(dots)*v and denominator D[b][t] += sum_j
// exp(dots) with global fp32 atomics (the logsumexp combine collapses to N/D).
// LDS: LSTR=68 pad + j = tx+16jj mapping -> <=2-way patterns everywhere
// (verified R2: conflicts 3.0e8 -> 7.3e6). P tile ALIASES the K tile (K dead
// after dots; extra barrier between dots-read and P-write) -> 53 KB LDS ->
// 3 blocks/CU instead of 2 (R3 was latency-bound at OccupancyPercent 20.6,
// VALUBusy 32%). Hot loops keep live ranges small (one qa/pr float4 at a
// time, unroll 2) to avoid the R2 scratch-spill regression.
// ---------------------------------------------------------------------------
__global__ __launch_bounds__(256, 3) void lsh_attn_kernel(
    const float* __restrict__ qk, const float* __restrict__ v,
    const int* __restrict__ st, float* __restrict__ Nbuf, float* __restrict__ Dbuf)
{
    __shared__ float Qs[64 * LSTR];
    __shared__ float Ks[64 * LSTR];      // doubles as the P tile after dots
    __shared__ float Vs[64 * LSTR];
    __shared__ int   tq[64];
    __shared__ int   tk[64];
    __shared__ float Drow[64];

    float* Ps = Ks;                      // alias: K consumed by dots, then P

    int tid = threadIdx.x;
    int bc = blockIdx.x;
    int b = bc >> 9, c = bc & (NCHUNK - 1);
    int cm = (c + NCHUNK - 1) & (NCHUNK - 1);

    const int*   stb = st + (size_t)b * (NHASH * SEQ);
    const float* qkb = qk + (size_t)b * SEQ * DIM;
    const float* vb  = v  + (size_t)b * SEQ * DIM;

    if (tid < 64) { tq[tid] = stb[c * 64 + tid]; Drow[tid] = 0.f; }
    __syncthreads();                     // tq visible

    {   // load Q (unnormalized): 4 threads/row, 16 floats each
        int r = tid >> 2, s = tid & 3;
        const float4* s4 = (const float4*)(qkb + (size_t)tq[r] * DIM + s * 16);
        float4* d4 = (float4*)(Qs + r * LSTR + s * 16);
        d4[0] = s4[0]; d4[1] = s4[1]; d4[2] = s4[2]; d4[3] = s4[3];
    }

    int ty = tid >> 4, tx = tid & 15;    // ty in 0..15, tx in 0..15
    float acc[4][4];
#pragma unroll
    for (int a = 0; a < 4; ++a)
        acc[a][0] = acc[a][1] = acc[a][2] = acc[a][3] = 0.f;

    for (int half = 0; half < 2; ++half) {
        int ck = half ? cm : c;
        __syncthreads();                 // Q staged (h0) / prev PV done (h1)
        {   // load K (L2-normalized) + V + tk: 4 threads/row, 16 floats each
            int r = tid >> 2, s = tid & 3;
            int trow = stb[ck * 64 + r];         // direct, no pre-barrier
            if (s == 0) tk[r] = trow;
            const float4* k4 = (const float4*)(qkb + (size_t)trow * DIM + s * 16);
            float4 a0 = k4[0], a1 = k4[1], a2 = k4[2], a3 = k4[3];
            float ss = a0.x*a0.x + a0.y*a0.y + a0.z*a0.z + a0.w*a0.w
                     + a1.x*a1.x + a1.y*a1.y + a1.z*a1.z + a1.w*a1.w
                     + a2.x*a2.x + a2.y*a2.y + a2.z*a2.z + a2.w*a2.w
                     + a3.x*a3.x + a3.y*a3.y + a3.z*a3.z + a3.w*a3.w;
            ss += __shfl_xor(ss, 1);
            ss += __shfl_xor(ss, 2);
            float sc = 1.0f / fmaxf(sqrtf(ss), 1e-12f);
            float4* kd = (float4*)(Ks + r * LSTR + s * 16);
            a0.x *= sc; a0.y *= sc; a0.z *= sc; a0.w *= sc;
            a1.x *= sc; a1.y *= sc; a1.z *= sc; a1.w *= sc;
            a2.x *= sc; a2.y *= sc; a2.z *= sc; a2.w *= sc;
            a3.x *= sc; a3.y *= sc; a3.z *= sc; a3.w *= sc;
            kd[0] = a0; kd[1] = a1; kd[2] = a2; kd[3] = a3;
            const float4* v4 = (const float4*)(vb + (size_t)trow * DIM + s * 16);
            float4* vd = (float4*)(Vs + r * LSTR + s * 16);
            vd[0] = v4[0]; vd[1] = v4[1]; vd[2] = v4[2]; vd[3] = v4[3];
        }
        __syncthreads();                 // K/V/tk staged
        float dt[4][4];
        {   // dots: thread tile i = ty+16a (4 rows) x j = tx+16jj (4 cols)
#pragma unroll
            for (int a = 0; a < 4; ++a)
                dt[a][0] = dt[a][1] = dt[a][2] = dt[a][3] = 0.f;
#pragma unroll 2
            for (int k = 0; k < 64; k += 4) {
                float4 kv[4];
#pragma unroll
                for (int jj = 0; jj < 4; ++jj)
                    kv[jj] = *(const float4*)(Ks + (tx + 16*jj) * LSTR + k);
#pragma unroll
                for (int a = 0; a < 4; ++a) {
                    float4 qa4 = *(const float4*)(Qs + (ty + 16*a) * LSTR + k);
                    const float* qa = (const float*)&qa4;
#pragma unroll
                    for (int jj = 0; jj < 4; ++jj) {
                        const float* kj = (const float*)&kv[jj];
                        dt[a][jj] = fmaf(qa[0], kj[0],
                                    fmaf(qa[1], kj[1],
                                    fmaf(qa[2], kj[2],
                                    fmaf(qa[3], kj[3], dt[a][jj]))));
                    }
                }
            }
        }
        __syncthreads();                 // all dots reads of Ks complete
        {   // mask self-attention, exp, write P into Ks (scalar, conflict-
            // free), shuffle-reduce row sums over the 16 tx lanes
#pragma unroll
            for (int a = 0; a < 4; ++a) {
                int i = ty + 16*a;
                int ti = tq[i];
                float rs = 0.f;
#pragma unroll
                for (int jj = 0; jj < 4; ++jj) {
                    int j = tx + 16*jj;
                    float p = (ti == tk[j]) ? 0.f : __expf(dt[a][jj] * 0.125f);
                    Ps[i * LSTR + j] = p;
                    rs += p;
                }
                rs += __shfl_xor(rs, 1);
                rs += __shfl_xor(rs, 2);
                rs += __shfl_xor(rs, 4);
                rs += __shfl_xor(rs, 8);
                if (tx == 0) Drow[i] += rs;   // unique owner (ty,a) -> row i
            }
        }
        __syncthreads();                 // P staged
        {   // PV accumulate: thread tile i = ty+16a x d = 4tx..4tx+3
#pragma unroll 2
            for (int j = 0; j < 64; j += 4) {
                float4 vr[4];
#pragma unroll
                for (int jj = 0; jj < 4; ++jj)
                    vr[jj] = *(const float4*)(Vs + (j + jj) * LSTR + 4*tx);
#pragma unroll
                for (int a = 0; a < 4; ++a) {
                    float4 pr4 = *(const float4*)(Ps + (ty + 16*a) * LSTR + j);
                    const float* pa = (const float*)&pr4;
#pragma unroll
                    for (int jj = 0; jj < 4; ++jj) {
                        const float* vj = (const float*)&vr[jj];
                        float p = pa[jj];
                        acc[a][0] = fmaf(p, vj[0], acc[a][0]);
                        acc[a][1] = fmaf(p, vj[1], acc[a][1]);
                        acc[a][2] = fmaf(p, vj[2], acc[a][2]);
                        acc[a][3] = fmaf(p, vj[3], acc[a][3]);
                    }
                }
            }
        }
    }
    __syncthreads();
    {   // scatter-accumulate into global N / D
#pragma unroll
        for (int a = 0; a < 4; ++a) {
            int i = ty + 16*a;
            int t = tq[i];
            float* np = Nbuf + ((size_t)b * SEQ + t) * DIM + 4*tx;
            atomicAdd(np + 0, acc[a][0]);
            atomicAdd(np + 1, acc[a][1]);
            atomicAdd(np + 2, acc[a][2]);
            atomicAdd(np + 3, acc[a][3]);
        }
        if (tid < 64) atomicAdd(&Dbuf[(size_t)b * SEQ + tq[tid]], Drow[tid]);
    }
}

// ---------------------------------------------------------------------------
// Kernel 0: zero-fill N/D accumulators (float4 stores; replaces memset)
// ---------------------------------------------------------------------------
__global__ __launch_bounds__(256) void lsh_zero_kernel(float4* __restrict__ p)
{
    p[blockIdx.x * 256 + threadIdx.x] = make_float4(0.f, 0.f, 0.f, 0.f);
}

// ---------------------------------------------------------------------------
// Kernel 4: out = N / D  (one float4 per thread)
// ---------------------------------------------------------------------------
__global__ __launch_bounds__(256) void lsh_combine_kernel(
    const float* __restrict__ Nbuf, const float* __restrict__ Dbuf,
    float* __restrict__ out)
{
    int gid = blockIdx.x * 256 + threadIdx.x;   // float4 index
    float4 n = ((const float4*)Nbuf)[gid];
    float d = Dbuf[gid >> 4];                   // 16 float4 per token
    float inv = 1.0f / d;
    float4 o;
    o.x = n.x * inv; o.y = n.y * inv; o.z = n.z * inv; o.w = n.w * inv;
    ((float4*)out)[gid] = o;
}

extern "C" void kernel_launch(void* const* d_in, const int* in_sizes, int n_in,
                              void* d_out, int out_size, void* d_ws, size_t ws_size,
                              hipStream_t stream)
{
    const float* qk  = (const float*)d_in[0];
    const float* v   = (const float*)d_in[1];
    const float* rot = (const float*)d_in[2];
    float* out = (float*)d_out;

    char* w = (char*)d_ws;
    // workspace layout (21.3 MB total):
    //   [0, 2MB)      buckets  : int[16*8*4096]
    //   [2MB, 4MB)    st       : int[16*8*4096]
    //   [4MB, 20MB)   Nbuf     : float[16*4096*64]
    //   [20MB, +256K) Dbuf     : float[16*4096]
    int*   buckets = (int*)(w);
    int*   st      = (int*)(w + 2097152);
    float* Nbuf    = (float*)(w + 4194304);
    float* Dbuf    = (float*)(w + 4194304 + 16777216);

    // zero Nbuf+Dbuf: (16777216 + 262144)/16 = 1064960 float4 = 4160 blocks
    lsh_zero_kernel<<<4160, 256, 0, stream>>>((float4*)(w + 4194304));
    lsh_hash_kernel<<<256, 256, 0, stream>>>(qk, rot, buckets);
    lsh_sort_kernel<<<128, 64, 0, stream>>>(buckets, st);
    lsh_attn_kernel<<<8192, 256, 0, stream>>>(qk, v, st, Nbuf, Dbuf);
    lsh_combine_kernel<<<4096, 256, 0, stream>>>(Nbuf, Dbuf, out);
}

// Round 5
// 443.187 us; speedup vs baseline: 5.5111x; 1.5105x over previous
//
#include <hip/hip_runtime.h>

#define BATCH  16
#define SEQ    4096
#define DIM    64
#define NHASH  8
#define NCHUNK 512   // chunks per batch row (NHASH * SEQ / 64)
#define LSTR   68    // LDS row stride in floats: 68*4=272 B, 16B-aligned,
                     // rotates banks by 4 per row -> conflict-free patterns

// ---------------------------------------------------------------------------
// Kernel 1: LSH hashing. One thread per (b,t) token. rotations are read with
// wave-uniform indices -> scalar loads through sL1. Per-thread q row lives in
// a private LDS column (dynamic f-indexing without VGPR-array spills).
// buckets[(b*8+h)*4096 + t] = argmax over [r, -r] (first-max wins, like jnp).
// ---------------------------------------------------------------------------
__global__ __launch_bounds__(256) void lsh_hash_kernel(
    const float* __restrict__ qk, const float* __restrict__ rot,
    int* __restrict__ buckets)
{
    __shared__ float qs[256 * DIM];
    int tid = threadIdx.x;
    int gid = blockIdx.x * 256 + tid;      // b*4096 + t
    int b = gid >> 12, t = gid & 4095;

    const float4* src = (const float4*)(qk + (size_t)gid * DIM);
#pragma unroll
    for (int u = 0; u < 16; ++u) {
        float4 x = src[u];
        qs[(4*u + 0) * 256 + tid] = x.x;
        qs[(4*u + 1) * 256 + tid] = x.y;
        qs[(4*u + 2) * 256 + tid] = x.z;
        qs[(4*u + 3) * 256 + tid] = x.w;
    }
    // no __syncthreads needed: each thread reads only its own column

    for (int h = 0; h < NHASH; ++h) {
        float acc[32];
#pragma unroll
        for (int i = 0; i < 32; ++i) acc[i] = 0.f;
        for (int f = 0; f < DIM; ++f) {
            float qf = qs[f * 256 + tid];
            const float* rp = rot + (f * NHASH + h) * 32;   // wave-uniform addr
#pragma unroll
            for (int i = 0; i < 32; ++i) acc[i] = fmaf(qf, rp[i], acc[i]);
        }
        float best = acc[0]; int bi = 0;
#pragma unroll
        for (int i = 1; i < 32; ++i) { if (acc[i] > best) { best = acc[i]; bi = i; } }
#pragma unroll
        for (int i = 0; i < 32; ++i) { float nv = -acc[i]; if (nv > best) { best = nv; bi = i + 32; } }
        buckets[((size_t)b * NHASH + h) * SEQ + t] = bi;
    }
}

// ---------------------------------------------------------------------------
// Kernel 2: stable counting sort per (b,h). One wave per block. Lane l owns
// tokens [64l, 64l+64) (contiguous -> stability). hist[lane][bucket] local
// histograms, column prefix over lanes by lane==bucket, then ordered scatter.
// st[pos] = original token t, sorted by (bucket, t); inv[t] = pos (inverse).
// ---------------------------------------------------------------------------
__global__ __launch_bounds__(64) void lsh_sort_kernel(
    const int* __restrict__ buckets, int* __restrict__ st, int* __restrict__ inv)
{
    int bh = blockIdx.x;                 // b*8 + h
    int lane = threadIdx.x;              // 0..63
    const int* bp = buckets + (size_t)bh * SEQ;
    __shared__ int hist[64 * 64];        // [lane][bucket]
    __shared__ int tot[64];
    __shared__ int base[64];

    for (int i = 0; i < 64; ++i) hist[(lane << 6) + i] = 0;
    __syncthreads();
    for (int u = 0; u < 64; ++u) {
        int tt = (lane << 6) + u;
        hist[(lane << 6) + bp[tt]] += 1;     // private region, no race
    }
    __syncthreads();
    {   // lane == bucket: exclusive prefix over lanes, total per bucket
        int run = 0;
        for (int l = 0; l < 64; ++l) {
            int idx = (l << 6) + lane;
            int c0 = hist[idx];
            hist[idx] = run;
            run += c0;
        }
        tot[lane] = run;
    }
    __syncthreads();
    if (lane == 0) {
        int r = 0;
        for (int i = 0; i < 64; ++i) { base[i] = r; r += tot[i]; }
    }
    __syncthreads();
    int* op = st  + (size_t)bh * SEQ;
    int* ip = inv + (size_t)bh * SEQ;
    for (int u = 0; u < 64; ++u) {
        int tt = (lane << 6) + u;
        int bb = bp[tt];
        int idx = (lane << 6) + bb;
        int pos = base[bb] + hist[idx];
        hist[idx] = pos - base[bb] + 1;
        op[pos] = tt;
        ip[tt] = pos;
    }
}

// ---------------------------------------------------------------------------
// Kernel 3: chunked attention. Block = one (b, chunk). Keys processed in two
// 64-row halves: own chunk, then look-back chunk (c-1 mod 512).
// direct=1: write un-normalized O rows + denominators to per-hash contiguous
// buffers (each line written by exactly ONE block -> no atomics, no cross-XCD
// L2 ping-pong; R4 showed 540 MB HBM writes vs ~150 MB logical from the
// atomic path's coherence churn). direct=0: legacy atomic accumulate.
// LDS: LSTR=68 pad + j = tx+16jj mapping -> <=2-way patterns (verified R2).
// P aliases K (53 KB -> 3 blocks/CU, verified R4). Hot loops keep live ranges
// small (one qa/pr float4 at a time, unroll 2) to avoid R2's spill regression.
// ---------------------------------------------------------------------------
__global__ __launch_bounds__(256, 3) void lsh_attn_kernel(
    const float* __restrict__ qk, const float* __restrict__ v,
    const int* __restrict__ st, float* __restrict__ Obuf, float* __restrict__ Dbuf,
    int direct)
{
    __shared__ float Qs[64 * LSTR];
    __shared__ float Ks[64 * LSTR];      // doubles as the P tile after dots
    __shared__ float Vs[64 * LSTR];
    __shared__ int   tq[64];
    __shared__ int   tk[64];
    __shared__ float Drow[64];

    float* Ps = Ks;                      // alias: K consumed by dots, then P

    int tid = threadIdx.x;
    int bc = blockIdx.x;
    int b = bc >> 9, c = bc & (NCHUNK - 1);
    int cm = (c + NCHUNK - 1) & (NCHUNK - 1);

    const int*   stb = st + (size_t)b * (NHASH * SEQ);
    const float* qkb = qk + (size_t)b * SEQ * DIM;
    const float* vb  = v  + (size_t)b * SEQ * DIM;

    if (tid < 64) { tq[tid] = stb[c * 64 + tid]; Drow[tid] = 0.f; }
    __syncthreads();                     // tq visible

    {   // load Q (unnormalized): 4 threads/row, 16 floats each
        int r = tid >> 2, s = tid & 3;
        const float4* s4 = (const float4*)(qkb + (size_t)tq[r] * DIM + s * 16);
        float4* d4 = (float4*)(Qs + r * LSTR + s * 16);
        d4[0] = s4[0]; d4[1] = s4[1]; d4[2] = s4[2]; d4[3] = s4[3];
    }

    int ty = tid >> 4, tx = tid & 15;    // ty in 0..15, tx in 0..15
    float acc[4][4];
#pragma unroll
    for (int a = 0; a < 4; ++a)
        acc[a][0] = acc[a][1] = acc[a][2] = acc[a][3] = 0.f;

    for (int half = 0; half < 2; ++half) {
        int ck = half ? cm : c;
        __syncthreads();                 // Q staged (h0) / prev PV done (h1)
        {   // load K (L2-normalized) + V + tk: 4 threads/row, 16 floats each
            int r = tid >> 2, s = tid & 3;
            int trow = stb[ck * 64 + r];         // direct, no pre-barrier
            if (s == 0) tk[r] = trow;
            const float4* k4 = (const float4*)(qkb + (size_t)trow * DIM + s * 16);
            float4 a0 = k4[0], a1 = k4[1], a2 = k4[2], a3 = k4[3];
            float ss = a0.x*a0.x + a0.y*a0.y + a0.z*a0.z + a0.w*a0.w
                     + a1.x*a1.x + a1.y*a1.y + a1.z*a1.z + a1.w*a1.w
                     + a2.x*a2.x + a2.y*a2.y + a2.z*a2.z + a2.w*a2.w
                     + a3.x*a3.x + a3.y*a3.y + a3.z*a3.z + a3.w*a3.w;
            ss += __shfl_xor(ss, 1);
            ss += __shfl_xor(ss, 2);
            float sc = 1.0f / fmaxf(sqrtf(ss), 1e-12f);
            float4* kd = (float4*)(Ks + r * LSTR + s * 16);
            a0.x *= sc; a0.y *= sc; a0.z *= sc; a0.w *= sc;
            a1.x *= sc; a1.y *= sc; a1.z *= sc; a1.w *= sc;
            a2.x *= sc; a2.y *= sc; a2.z *= sc; a2.w *= sc;
            a3.x *= sc; a3.y *= sc; a3.z *= sc; a3.w *= sc;
            kd[0] = a0; kd[1] = a1; kd[2] = a2; kd[3] = a3;
            const float4* v4 = (const float4*)(vb + (size_t)trow * DIM + s * 16);
            float4* vd = (float4*)(Vs + r * LSTR + s * 16);
            vd[0] = v4[0]; vd[1] = v4[1]; vd[2] = v4[2]; vd[3] = v4[3];
        }
        __syncthreads();                 // K/V/tk staged
        float dt[4][4];
        {   // dots: thread tile i = ty+16a (4 rows) x j = tx+16jj (4 cols)
#pragma unroll
            for (int a = 0; a < 4; ++a)
                dt[a][0] = dt[a][1] = dt[a][2] = dt[a][3] = 0.f;
#pragma unroll 2
            for (int k = 0; k < 64; k += 4) {
                float4 kv[4];
#pragma unroll
                for (int jj = 0; jj < 4; ++jj)
                    kv[jj] = *(const float4*)(Ks + (tx + 16*jj) * LSTR + k);
#pragma unroll
                for (int a = 0; a < 4; ++a) {
                    float4 qa4 = *(const float4*)(Qs + (ty + 16*a) * LSTR + k);
                    const float* qa = (const float*)&qa4;
#pragma unroll
                    for (int jj = 0; jj < 4; ++jj) {
                        const float* kj = (const float*)&kv[jj];
                        dt[a][jj] = fmaf(qa[0], kj[0],
                                    fmaf(qa[1], kj[1],
                                    fmaf(qa[2], kj[2],
                                    fmaf(qa[3], kj[3], dt[a][jj]))));
                    }
                }
            }
        }
        __syncthreads();                 // all dots reads of Ks complete
        {   // mask self-attention, exp, write P into Ks (scalar, conflict-
            // free), shuffle-reduce row sums over the 16 tx lanes
#pragma unroll
            for (int a = 0; a < 4; ++a) {
                int i = ty + 16*a;
                int ti = tq[i];
                float rs = 0.f;
#pragma unroll
                for (int jj = 0; jj < 4; ++jj) {
                    int j = tx + 16*jj;
                    float p = (ti == tk[j]) ? 0.f : __expf(dt[a][jj] * 0.125f);
                    Ps[i * LSTR + j] = p;
                    rs += p;
                }
                rs += __shfl_xor(rs, 1);
                rs += __shfl_xor(rs, 2);
                rs += __shfl_xor(rs, 4);
                rs += __shfl_xor(rs, 8);
                if (tx == 0) Drow[i] += rs;   // unique owner (ty,a) -> row i
            }
        }
        __syncthreads();                 // P staged
        {   // PV accumulate: thread tile i = ty+16a x d = 4tx..4tx+3
#pragma unroll 2
            for (int j = 0; j < 64; j += 4) {
                float4 vr[4];
#pragma unroll
                for (int jj = 0; jj < 4; ++jj)
                    vr[jj] = *(const float4*)(Vs + (j + jj) * LSTR + 4*tx);
#pragma unroll
                for (int a = 0; a < 4; ++a) {
                    float4 pr4 = *(const float4*)(Ps + (ty + 16*a) * LSTR + j);
                    const float* pa = (const float*)&pr4;
#pragma unroll
                    for (int jj = 0; jj < 4; ++jj) {
                        const float* vj = (const float*)&vr[jj];
                        float p = pa[jj];
                        acc[a][0] = fmaf(p, vj[0], acc[a][0]);
                        acc[a][1] = fmaf(p, vj[1], acc[a][1]);
                        acc[a][2] = fmaf(p, vj[2], acc[a][2]);
                        acc[a][3] = fmaf(p, vj[3], acc[a][3]);
                    }
                }
            }
        }
    }
    __syncthreads();
    if (direct) {
        // contention-free epilogue: O row = sorted position (b*32768 + c*64+i)
        size_t base = ((size_t)b * (NHASH * SEQ)) + (size_t)c * 64;
#pragma unroll
        for (int a = 0; a < 4; ++a) {
            int i = ty + 16*a;
            float4 o; o.x = acc[a][0]; o.y = acc[a][1]; o.z = acc[a][2]; o.w = acc[a][3];
            *(float4*)(Obuf + (base + i) * DIM + 4*tx) = o;
        }
        if (tid < 64) Dbuf[base + tid] = Drow[tid];
    } else {
        // legacy atomic accumulate into N[b][t][d] / D[b][t]
#pragma unroll
        for (int a = 0; a < 4; ++a) {
            int i = ty + 16*a;
            int t = tq[i];
            float* np = Obuf + ((size_t)b * SEQ + t) * DIM + 4*tx;
            atomicAdd(np + 0, acc[a][0]);
            atomicAdd(np + 1, acc[a][1]);
            atomicAdd(np + 2, acc[a][2]);
            atomicAdd(np + 3, acc[a][3]);
        }
        if (tid < 64) atomicAdd(&Dbuf[(size_t)b * SEQ + tq[tid]], Drow[tid]);
    }
}

// ---------------------------------------------------------------------------
// Kernel 4a (direct): out[b,t] = sum_h O_h[inv_h(t)] / sum_h D_h[inv_h(t)].
// 16 d4-threads per token -> each hash-row gather is a 256 B coalesced read.
// ---------------------------------------------------------------------------
__global__ __launch_bounds__(256) void lsh_combine_direct(
    const float* __restrict__ Obuf, const float* __restrict__ Dbuf,
    const int* __restrict__ inv, float* __restrict__ out)
{
    int gid = blockIdx.x * 256 + threadIdx.x;   // b*65536 + t*16 + d4
    int d4 = gid & 15;
    int t  = (gid >> 4) & (SEQ - 1);
    int b  = gid >> 16;

    float4 n = make_float4(0.f, 0.f, 0.f, 0.f);
    float den = 0.f;
#pragma unroll
    for (int h = 0; h < NHASH; ++h) {
        int bh = b * NHASH + h;
        int pos = inv[((size_t)bh << 12) + t];
        size_t row = ((size_t)bh << 12) + pos;
        float4 o = ((const float4*)Obuf)[row * 16 + d4];
        den += Dbuf[row];
        n.x += o.x; n.y += o.y; n.z += o.z; n.w += o.w;
    }
    float invd = 1.0f / den;
    float4 r; r.x = n.x*invd; r.y = n.y*invd; r.z = n.z*invd; r.w = n.w*invd;
    ((float4*)out)[gid] = r;
}

// ---------------------------------------------------------------------------
// Kernel 4b (fallback): out = N / D  (one float4 per thread)
// ---------------------------------------------------------------------------
__global__ __launch_bounds__(256) void lsh_combine_atomic(
    const float* __restrict__ Nbuf, const float* __restrict__ Dbuf,
    float* __restrict__ out)
{
    int gid = blockIdx.x * 256 + threadIdx.x;   // float4 index
    float4 n = ((const float4*)Nbuf)[gid];
    float d = Dbuf[gid >> 4];                   // 16 float4 per token
    float inv = 1.0f / d;
    float4 o;
    o.x = n.x * inv; o.y = n.y * inv; o.z = n.z * inv; o.w = n.w * inv;
    ((float4*)out)[gid] = o;
}

// ---------------------------------------------------------------------------
// Kernel 0 (fallback only): zero-fill N/D accumulators
// ---------------------------------------------------------------------------
__global__ __launch_bounds__(256) void lsh_zero_kernel(float4* __restrict__ p)
{
    p[blockIdx.x * 256 + threadIdx.x] = make_float4(0.f, 0.f, 0.f, 0.f);
}

extern "C" void kernel_launch(void* const* d_in, const int* in_sizes, int n_in,
                              void* d_out, int out_size, void* d_ws, size_t ws_size,
                              hipStream_t stream)
{
    const float* qk  = (const float*)d_in[0];
    const float* v   = (const float*)d_in[1];
    const float* rot = (const float*)d_in[2];
    float* out = (float*)d_out;

    char* w = (char*)d_ws;
    // common layout:
    //   [0, 2MB)   buckets : int[16*8*4096]
    //   [2, 4MB)   st      : int[16*8*4096]
    //   [4, 6MB)   inv     : int[16*8*4096]
    int* buckets = (int*)(w);
    int* st      = (int*)(w + 2097152);
    int* inv     = (int*)(w + 4194304);

    // direct path:   [6MB, +134.2MB) Obuf fp32[16*8*4096*64], then Dbuf fp32[16*8*4096]
    // fallback path: [6MB, +16.8MB)  Nbuf fp32[16*4096*64],    then Dbuf fp32[16*4096]
    const size_t DIRECT_NEED = 6291456ull + 134217728ull + 2097152ull; // 142.6 MB
    int direct = (ws_size >= DIRECT_NEED) ? 1 : 0;

    lsh_hash_kernel<<<256, 256, 0, stream>>>(qk, rot, buckets);
    lsh_sort_kernel<<<128, 64, 0, stream>>>(buckets, st, inv);

    if (direct) {
        float* Obuf = (float*)(w + 6291456);
        float* Dbuf = (float*)(w + 6291456 + 134217728);
        lsh_attn_kernel<<<8192, 256, 0, stream>>>(qk, v, st, Obuf, Dbuf, 1);
        lsh_combine_direct<<<4096, 256, 0, stream>>>(Obuf, Dbuf, inv, out);
    } else {
        float* Nbuf = (float*)(w + 6291456);
        float* Dbuf = (float*)(w + 6291456 + 16777216);
        lsh_zero_kernel<<<4160, 256, 0, stream>>>((float4*)(w + 6291456));
        lsh_attn_kernel<<<8192, 256, 0, stream>>>(qk, v, st, Nbuf, Dbuf, 0);
        lsh_combine_atomic<<<4096, 256, 0, stream>>>(Nbuf, Dbuf, out);
    }
}

// Round 6
// 368.767 us; speedup vs baseline: 6.6233x; 1.2018x over previous
//
#include <hip/hip_runtime.h>

#define BATCH  16
#define SEQ    4096
#define DIM    64
#define NHASH  8
#define NCHUNK 512   // chunks per batch row (NHASH * SEQ / 64)
#define SB     72    // bf16 LDS row stride: 72*2=144 B, 16B-aligned for b128

typedef __attribute__((ext_vector_type(8))) short short8;   // 8 bf16 (4 VGPR)
typedef __attribute__((ext_vector_type(4))) float floatx4;  // MFMA C/D

__device__ __forceinline__ float trunc_hi(float a) {
    return __uint_as_float(__float_as_uint(a) & 0xffff0000u);
}
__device__ __forceinline__ unsigned pack_hi2(float a, float b) {
    return (__float_as_uint(a) >> 16) | (__float_as_uint(b) & 0xffff0000u);
}
// split 16 fp32 -> 16 bf16 hi + 16 bf16 lo (truncation split: x = hi + lo +
// O(2^-14 x)); store as 2x uint4 each (dst element offsets 16B-aligned).
__device__ __forceinline__ void split16_store(const float* xs, short* hiDst, short* loDst) {
    unsigned hd[8], ld[8];
#pragma unroll
    for (int u = 0; u < 8; ++u) {
        float a = xs[2*u], b = xs[2*u + 1];
        hd[u] = pack_hi2(a, b);
        ld[u] = pack_hi2(a - trunc_hi(a), b - trunc_hi(b));
    }
    *(uint4*)(hiDst)     = make_uint4(hd[0], hd[1], hd[2], hd[3]);
    *(uint4*)(hiDst + 8) = make_uint4(hd[4], hd[5], hd[6], hd[7]);
    *(uint4*)(loDst)     = make_uint4(ld[0], ld[1], ld[2], ld[3]);
    *(uint4*)(loDst + 8) = make_uint4(ld[4], ld[5], ld[6], ld[7]);
}

// ---------------------------------------------------------------------------
// Kernel 1: LSH hashing. 128 tokens/block (32 KB LDS -> ~5 blocks/CU vs 1 at
// 64 KB in R5 -- the kernel was latency-bound at 4 waves/CU). Thread (tt,hg):
// token tt = tid&127, h-group hg = tid>>7 computes h in [4hg, 4hg+4). hg is
// wave-uniform so rot addresses stay scalar. argmax first-max-wins like jnp.
// ---------------------------------------------------------------------------
__global__ __launch_bounds__(256) void lsh_hash_kernel(
    const float* __restrict__ qk, const float* __restrict__ rot,
    int* __restrict__ buckets)
{
    __shared__ float qs[DIM * 128];
    int tid = threadIdx.x;
    int tt = tid & 127;
    int hg = tid >> 7;                     // wave-uniform (waves 0,1 -> 0; 2,3 -> 1)
    int gid = blockIdx.x * 128 + tt;       // b*4096 + t
    int b = gid >> 12, t = gid & 4095;

    const float4* src = (const float4*)(qk + (size_t)gid * DIM + hg * 32);
#pragma unroll
    for (int u = 0; u < 8; ++u) {
        float4 x = src[u];
        int f = hg * 32 + 4 * u;
        qs[(f + 0) * 128 + tt] = x.x;
        qs[(f + 1) * 128 + tt] = x.y;
        qs[(f + 2) * 128 + tt] = x.z;
        qs[(f + 3) * 128 + tt] = x.w;
    }
    __syncthreads();

    for (int h0 = 0; h0 < 4; ++h0) {
        int h = hg * 4 + h0;
        float acc[32];
#pragma unroll
        for (int i = 0; i < 32; ++i) acc[i] = 0.f;
        for (int f = 0; f < DIM; ++f) {
            float qf = qs[f * 128 + tt];
            const float* rp = rot + (f * NHASH + h) * 32;   // wave-uniform addr
#pragma unroll
            for (int i = 0; i < 32; ++i) acc[i] = fmaf(qf, rp[i], acc[i]);
        }
        float best = acc[0]; int bi = 0;
#pragma unroll
        for (int i = 1; i < 32; ++i) { if (acc[i] > best) { best = acc[i]; bi = i; } }
#pragma unroll
        for (int i = 0; i < 32; ++i) { float nv = -acc[i]; if (nv > best) { best = nv; bi = i + 32; } }
        buckets[((size_t)b * NHASH + h) * SEQ + t] = bi;
    }
}

// ---------------------------------------------------------------------------
// Kernel 2: stable counting sort per (b,h). One wave per block. Lane l owns
// tokens [64l, 64l+64) (contiguous -> stability). st[pos] = token, inv[t]=pos.
// ---------------------------------------------------------------------------
__global__ __launch_bounds__(64) void lsh_sort_kernel(
    const int* __restrict__ buckets, int* __restrict__ st, int* __restrict__ inv)
{
    int bh = blockIdx.x;
    int lane = threadIdx.x;
    const int* bp = buckets + (size_t)bh * SEQ;
    __shared__ int hist[64 * 64];
    __shared__ int tot[64];
    __shared__ int base[64];

    for (int i = 0; i < 64; ++i) hist[(lane << 6) + i] = 0;
    __syncthreads();
    for (int u = 0; u < 64; ++u) {
        int tt = (lane << 6) + u;
        hist[(lane << 6) + bp[tt]] += 1;
    }
    __syncthreads();
    {
        int run = 0;
        for (int l = 0; l < 64; ++l) {
            int idx = (l << 6) + lane;
            int c0 = hist[idx];
            hist[idx] = run;
            run += c0;
        }
        tot[lane] = run;
    }
    __syncthreads();
    if (lane == 0) {
        int r = 0;
        for (int i = 0; i < 64; ++i) { base[i] = r; r += tot[i]; }
    }
    __syncthreads();
    int* op = st  + (size_t)bh * SEQ;
    int* ip = inv + (size_t)bh * SEQ;
    for (int u = 0; u < 64; ++u) {
        int tt = (lane << 6) + u;
        int bb = bp[tt];
        int idx = (lane << 6) + bb;
        int pos = base[bb] + hist[idx];
        hist[idx] = pos - base[bb] + 1;
        op[pos] = tt;
        ip[tt] = pos;
    }
}

// ---------------------------------------------------------------------------
// Kernel 3: MFMA attention. Block = (b, chunk); wave w owns query strip
// 16w..16w+15. fp32 matmuls via split-bf16 (hi+lo truncation, 3 MFMAs per
// product, residual ~2^-14). Layouts (verified per guide m89/m118): A-frag
// A[m=lane&15][k=quad*8+j] from row-major [m][k]; B-frag B[k][n=lane&15]
// from [n][k] storage -> K natural (dots), V transposed (PV); C/D:
// row=quad*4+reg, col=lane&15. P strip is wave-private: written after dots,
// read as PV A-operand with NO barrier. exp/denominator in fp32 before split.
// 2 barriers/half. LDS 74 KB -> 2 blocks/CU. Epilogue = R5's contention-free
// per-hash O/D rows (no atomics).
// ---------------------------------------------------------------------------
__global__ __launch_bounds__(256, 2) void lsh_attn_kernel(
    const float* __restrict__ qk, const float* __restrict__ v,
    const int* __restrict__ st, float* __restrict__ Obuf, float* __restrict__ Dbuf)
{
    __shared__ short Qhi[64 * SB], Qlo[64 * SB];
    __shared__ short Khi[64 * SB], Klo[64 * SB];
    __shared__ short Vhi[64 * SB], Vlo[64 * SB];   // transposed: [dim][key]
    __shared__ short Phi[64 * SB], Plo[64 * SB];   // [query][key]
    __shared__ int   tq[64], tk[64];

    int tid  = threadIdx.x;
    int lane = tid & 63;
    int w    = tid >> 6;          // wave id = query-strip / V key-group
    int quad = lane >> 4;
    int l15  = lane & 15;

    int bc = blockIdx.x;
    int b = bc >> 9, c = bc & (NCHUNK - 1);
    int cm = (c + NCHUNK - 1) & (NCHUNK - 1);

    const int*   stb = st + (size_t)b * (NHASH * SEQ);
    const float* qkb = qk + (size_t)b * SEQ * DIM;
    const float* vb  = v  + (size_t)b * SEQ * DIM;

    if (tid < 64) tq[tid] = stb[c * 64 + tid];
    __syncthreads();

    {   // stage Q split: 4 threads/row, 16 dims each
        int r = tid >> 2, s = tid & 3;
        const float4* s4 = (const float4*)(qkb + (size_t)tq[r] * DIM + s * 16);
        float xs[16];
        *(float4*)&xs[0]  = s4[0];
        *(float4*)&xs[4]  = s4[1];
        *(float4*)&xs[8]  = s4[2];
        *(float4*)&xs[12] = s4[3];
        split16_store(xs, &Qhi[r * SB + s * 16], &Qlo[r * SB + s * 16]);
    }

    float   Dacc[4] = {0.f, 0.f, 0.f, 0.f};
    floatx4 oacc[4];
#pragma unroll
    for (int a = 0; a < 4; ++a) oacc[a] = (floatx4){0.f, 0.f, 0.f, 0.f};

    for (int half = 0; half < 2; ++half) {
        int ck = half ? cm : c;
        __syncthreads();              // Q staged (h0) / prev-half PV reads done (h1)

        {   // stage K (L2-normalized) split: 4 threads/row
            int r = tid >> 2, s = tid & 3;
            int trow = stb[ck * 64 + r];
            if (s == 0) tk[r] = trow;
            const float4* k4 = (const float4*)(qkb + (size_t)trow * DIM + s * 16);
            float xs[16];
            *(float4*)&xs[0]  = k4[0];
            *(float4*)&xs[4]  = k4[1];
            *(float4*)&xs[8]  = k4[2];
            *(float4*)&xs[12] = k4[3];
            float ss = 0.f;
#pragma unroll
            for (int u = 0; u < 16; ++u) ss += xs[u] * xs[u];
            ss += __shfl_xor(ss, 1);
            ss += __shfl_xor(ss, 2);
            float sc = 1.0f / fmaxf(sqrtf(ss), 1e-12f);
#pragma unroll
            for (int u = 0; u < 16; ++u) xs[u] *= sc;
            split16_store(xs, &Khi[r * SB + s * 16], &Klo[r * SB + s * 16]);
        }
        {   // stage V TRANSPOSED split: thread = dim lane, keys w*16..w*16+15
            float xs[16];
#pragma unroll
            for (int u = 0; u < 16; ++u) {
                int trow = stb[ck * 64 + w * 16 + u];     // wave-uniform
                xs[u] = vb[(size_t)trow * DIM + lane];    // coalesced 256B row
            }
            split16_store(xs, &Vhi[lane * SB + w * 16], &Vlo[lane * SB + w * 16]);
        }
        __syncthreads();              // K, Vt, tk staged

        // dots: D = Q·K^T over 4 key-tiles, K=64 = 2 k-blocks, 3-term split
        floatx4 dt[4];
#pragma unroll
        for (int jt = 0; jt < 4; ++jt) dt[jt] = (floatx4){0.f, 0.f, 0.f, 0.f};
#pragma unroll
        for (int kb = 0; kb < 2; ++kb) {
            short8 aH = *(const short8*)&Qhi[(16 * w + l15) * SB + kb * 32 + quad * 8];
            short8 aL = *(const short8*)&Qlo[(16 * w + l15) * SB + kb * 32 + quad * 8];
#pragma unroll
            for (int jt = 0; jt < 4; ++jt) {
                short8 bH = *(const short8*)&Khi[(16 * jt + l15) * SB + kb * 32 + quad * 8];
                short8 bL = *(const short8*)&Klo[(16 * jt + l15) * SB + kb * 32 + quad * 8];
                dt[jt] = __builtin_amdgcn_mfma_f32_16x16x32_bf16(aH, bH, dt[jt], 0, 0, 0);
                dt[jt] = __builtin_amdgcn_mfma_f32_16x16x32_bf16(aL, bH, dt[jt], 0, 0, 0);
                dt[jt] = __builtin_amdgcn_mfma_f32_16x16x32_bf16(aH, bL, dt[jt], 0, 0, 0);
            }
        }

        // mask + exp (fp32) + wave-private P split-write + denominator partials
        int tqr[4];
#pragma unroll
        for (int r = 0; r < 4; ++r) tqr[r] = tq[16 * w + quad * 4 + r];
#pragma unroll
        for (int jt = 0; jt < 4; ++jt) {
            int tkc = tk[16 * jt + l15];
#pragma unroll
            for (int r = 0; r < 4; ++r) {
                float p = (tqr[r] == tkc) ? 0.f : __expf(dt[jt][r] * 0.125f);
                Dacc[r] += p;
                int idx = (16 * w + quad * 4 + r) * SB + 16 * jt + l15;
                Phi[idx] = (short)(__float_as_uint(p) >> 16);
                Plo[idx] = (short)(__float_as_uint(p - trunc_hi(p)) >> 16);
            }
        }

        // PV: O += P·V (A = own P strip, B = Vt; no barrier needed)
#pragma unroll
        for (int kb = 0; kb < 2; ++kb) {
            short8 aH = *(const short8*)&Phi[(16 * w + l15) * SB + kb * 32 + quad * 8];
            short8 aL = *(const short8*)&Plo[(16 * w + l15) * SB + kb * 32 + quad * 8];
#pragma unroll
            for (int a = 0; a < 4; ++a) {
                short8 bH = *(const short8*)&Vhi[(16 * a + l15) * SB + kb * 32 + quad * 8];
                short8 bL = *(const short8*)&Vlo[(16 * a + l15) * SB + kb * 32 + quad * 8];
                oacc[a] = __builtin_amdgcn_mfma_f32_16x16x32_bf16(aH, bH, oacc[a], 0, 0, 0);
                oacc[a] = __builtin_amdgcn_mfma_f32_16x16x32_bf16(aL, bH, oacc[a], 0, 0, 0);
                oacc[a] = __builtin_amdgcn_mfma_f32_16x16x32_bf16(aH, bL, oacc[a], 0, 0, 0);
            }
        }
    }

    // epilogue: contention-free per-hash rows. oacc layout: row=quad*4+reg
    // (query within strip), col=l15 (dim within d-tile a).
    size_t base = (size_t)b * (NHASH * SEQ) + (size_t)c * 64;
#pragma unroll
    for (int a = 0; a < 4; ++a)
#pragma unroll
        for (int r = 0; r < 4; ++r)
            Obuf[(base + 16 * w + quad * 4 + r) * DIM + 16 * a + l15] = oacc[a][r];
#pragma unroll
    for (int r = 0; r < 4; ++r) {
        float rs = Dacc[r];
        rs += __shfl_xor(rs, 1);
        rs += __shfl_xor(rs, 2);
        rs += __shfl_xor(rs, 4);
        rs += __shfl_xor(rs, 8);
        if (l15 == 0) Dbuf[base + 16 * w + quad * 4 + r] = rs;
    }
}

// ---------------------------------------------------------------------------
// Kernel 4: out[b,t] = sum_h O_h[inv_h(t)] / sum_h D_h[inv_h(t)].
// ---------------------------------------------------------------------------
__global__ __launch_bounds__(256) void lsh_combine_direct(
    const float* __restrict__ Obuf, const float* __restrict__ Dbuf,
    const int* __restrict__ inv, float* __restrict__ out)
{
    int gid = blockIdx.x * 256 + threadIdx.x;   // b*65536 + t*16 + d4
    int d4 = gid & 15;
    int t  = (gid >> 4) & (SEQ - 1);
    int b  = gid >> 16;

    float4 n = make_float4(0.f, 0.f, 0.f, 0.f);
    float den = 0.f;
#pragma unroll
    for (int h = 0; h < NHASH; ++h) {
        int bh = b * NHASH + h;
        int pos = inv[((size_t)bh << 12) + t];
        size_t row = ((size_t)bh << 12) + pos;
        float4 o = ((const float4*)Obuf)[row * 16 + d4];
        den += Dbuf[row];
        n.x += o.x; n.y += o.y; n.z += o.z; n.w += o.w;
    }
    float invd = 1.0f / den;
    float4 r; r.x = n.x*invd; r.y = n.y*invd; r.z = n.z*invd; r.w = n.w*invd;
    ((float4*)out)[gid] = r;
}

extern "C" void kernel_launch(void* const* d_in, const int* in_sizes, int n_in,
                              void* d_out, int out_size, void* d_ws, size_t ws_size,
                              hipStream_t stream)
{
    const float* qk  = (const float*)d_in[0];
    const float* v   = (const float*)d_in[1];
    const float* rot = (const float*)d_in[2];
    float* out = (float*)d_out;

    char* w = (char*)d_ws;
    // workspace layout (142.6 MB):
    //   [0, 2MB)        buckets : int[16*8*4096]
    //   [2, 4MB)        st      : int[16*8*4096]
    //   [4, 6MB)        inv     : int[16*8*4096]
    //   [6MB, +134.2MB) Obuf    : fp32[16*8*4096*64]
    //   then            Dbuf    : fp32[16*8*4096]
    int*   buckets = (int*)(w);
    int*   st      = (int*)(w + 2097152);
    int*   inv     = (int*)(w + 4194304);
    float* Obuf    = (float*)(w + 6291456);
    float* Dbuf    = (float*)(w + 6291456 + 134217728);

    lsh_hash_kernel<<<512, 256, 0, stream>>>(qk, rot, buckets);
    lsh_sort_kernel<<<128, 64, 0, stream>>>(buckets, st, inv);
    lsh_attn_kernel<<<8192, 256, 0, stream>>>(qk, v, st, Obuf, Dbuf);
    lsh_combine_direct<<<4096, 256, 0, stream>>>(Obuf, Dbuf, inv, out);
}

// Round 7
// 330.006 us; speedup vs baseline: 7.4013x; 1.1175x over previous
//
#include <hip/hip_runtime.h>

#define BATCH  16
#define SEQ    4096
#define DIM    64
#define NHASH  8
#define NCHUNK 512   // chunks per batch row (NHASH * SEQ / 64)
#define SB     72    // bf16 LDS row stride: 72*2=144 B, 16B-aligned for b128

typedef __attribute__((ext_vector_type(8))) short short8;   // 8 bf16 (4 VGPR)
typedef __attribute__((ext_vector_type(4))) float floatx4;  // MFMA C/D

__device__ __forceinline__ float trunc_hi(float a) {
    return __uint_as_float(__float_as_uint(a) & 0xffff0000u);
}
__device__ __forceinline__ unsigned pack_hi2(float a, float b) {
    return (__float_as_uint(a) >> 16) | (__float_as_uint(b) & 0xffff0000u);
}
// split 16 fp32 -> 16 bf16 hi + 16 bf16 lo (truncation split: x = hi + lo +
// O(2^-14 x)); store as 2x uint4 each (dst element offsets 16B-aligned).
__device__ __forceinline__ void split16_store(const float* xs, short* hiDst, short* loDst) {
    unsigned hd[8], ld[8];
#pragma unroll
    for (int u = 0; u < 8; ++u) {
        float a = xs[2*u], b = xs[2*u + 1];
        hd[u] = pack_hi2(a, b);
        ld[u] = pack_hi2(a - trunc_hi(a), b - trunc_hi(b));
    }
    *(uint4*)(hiDst)     = make_uint4(hd[0], hd[1], hd[2], hd[3]);
    *(uint4*)(hiDst + 8) = make_uint4(hd[4], hd[5], hd[6], hd[7]);
    *(uint4*)(loDst)     = make_uint4(ld[0], ld[1], ld[2], ld[3]);
    *(uint4*)(loDst + 8) = make_uint4(ld[4], ld[5], ld[6], ld[7]);
}
// split 8 fp32 -> bf16 hi/lo short8 fragments in registers
__device__ __forceinline__ void split8_frag(const float* xs, short8* hi, short8* lo) {
    union { unsigned u[4]; short8 s; } H, L;
#pragma unroll
    for (int u = 0; u < 4; ++u) {
        float a = xs[2*u], b = xs[2*u + 1];
        H.u[u] = pack_hi2(a, b);
        L.u[u] = pack_hi2(a - trunc_hi(a), b - trunc_hi(b));
    }
    *hi = H.s; *lo = L.s;
}

// ---------------------------------------------------------------------------
// Kernel 1: LSH hashing. 128 tokens/block (32 KB LDS -> 5 blocks/CU). Thread
// (tt,hg): token tt = tid&127, h-group hg = tid>>7 (wave-uniform -> rot
// addresses stay scalar). argmax first-max-wins like jnp.
// ---------------------------------------------------------------------------
__global__ __launch_bounds__(256) void lsh_hash_kernel(
    const float* __restrict__ qk, const float* __restrict__ rot,
    int* __restrict__ buckets)
{
    __shared__ float qs[DIM * 128];
    int tid = threadIdx.x;
    int tt = tid & 127;
    int hg = tid >> 7;
    int gid = blockIdx.x * 128 + tt;       // b*4096 + t
    int b = gid >> 12, t = gid & 4095;

    const float4* src = (const float4*)(qk + (size_t)gid * DIM + hg * 32);
#pragma unroll
    for (int u = 0; u < 8; ++u) {
        float4 x = src[u];
        int f = hg * 32 + 4 * u;
        qs[(f + 0) * 128 + tt] = x.x;
        qs[(f + 1) * 128 + tt] = x.y;
        qs[(f + 2) * 128 + tt] = x.z;
        qs[(f + 3) * 128 + tt] = x.w;
    }
    __syncthreads();

    for (int h0 = 0; h0 < 4; ++h0) {
        int h = hg * 4 + h0;
        float acc[32];
#pragma unroll
        for (int i = 0; i < 32; ++i) acc[i] = 0.f;
        for (int f = 0; f < DIM; ++f) {
            float qf = qs[f * 128 + tt];
            const float* rp = rot + (f * NHASH + h) * 32;   // wave-uniform addr
#pragma unroll
            for (int i = 0; i < 32; ++i) acc[i] = fmaf(qf, rp[i], acc[i]);
        }
        float best = acc[0]; int bi = 0;
#pragma unroll
        for (int i = 1; i < 32; ++i) { if (acc[i] > best) { best = acc[i]; bi = i; } }
#pragma unroll
        for (int i = 0; i < 32; ++i) { float nv = -acc[i]; if (nv > best) { best = nv; bi = i + 32; } }
        buckets[((size_t)b * NHASH + h) * SEQ + t] = bi;
    }
}

// ---------------------------------------------------------------------------
// Kernel 2: stable counting sort per (b,h). One wave per block. Lane l owns
// tokens [64l, 64l+64) (contiguous -> stability). st[pos] = token, inv[t]=pos.
// ---------------------------------------------------------------------------
__global__ __launch_bounds__(64) void lsh_sort_kernel(
    const int* __restrict__ buckets, int* __restrict__ st, int* __restrict__ inv)
{
    int bh = blockIdx.x;
    int lane = threadIdx.x;
    const int* bp = buckets + (size_t)bh * SEQ;
    __shared__ int hist[64 * 64];
    __shared__ int tot[64];
    __shared__ int base[64];

    for (int i = 0; i < 64; ++i) hist[(lane << 6) + i] = 0;
    __syncthreads();
    for (int u = 0; u < 64; ++u) {
        int tt = (lane << 6) + u;
        hist[(lane << 6) + bp[tt]] += 1;
    }
    __syncthreads();
    {
        int run = 0;
        for (int l = 0; l < 64; ++l) {
            int idx = (l << 6) + lane;
            int c0 = hist[idx];
            hist[idx] = run;
            run += c0;
        }
        tot[lane] = run;
    }
    __syncthreads();
    if (lane == 0) {
        int r = 0;
        for (int i = 0; i < 64; ++i) { base[i] = r; r += tot[i]; }
    }
    __syncthreads();
    int* op = st  + (size_t)bh * SEQ;
    int* ip = inv + (size_t)bh * SEQ;
    for (int u = 0; u < 64; ++u) {
        int tt = (lane << 6) + u;
        int bb = bp[tt];
        int idx = (lane << 6) + bb;
        int pos = base[bb] + hist[idx];
        hist[idx] = pos - base[bb] + 1;
        op[pos] = tt;
        ip[tt] = pos;
    }
}

// ---------------------------------------------------------------------------
// Kernel 3: MFMA attention, occupancy-optimized (R6 was 49% idle at 2
// blocks/CU, 74 KB LDS). Changes vs R6:
//  - Q fragments live in REGISTERS (each wave reads only its own 16-row
//    strip; each lane's A-frag is a fixed 16-elem slice loaded straight from
//    global and hi/lo-split in regs) -> Q LDS tiles gone (-18.4 KB).
//  - P tiles alias the K tiles (K dead after dots; extra barrier between
//    dots-reads and P-writes; P rows stay wave-private so the P->PV handoff
//    still needs no barrier) (-18.4 KB).
//  - tq[] LDS dropped (mask row-ids loaded per-lane from global, hoisted).
// LDS 37.2 KB -> 4 blocks/CU (16 waves/CU). __launch_bounds__(256,4) caps
// VGPR at 128 (Q frags add ~16 to R6's 88; spills would show as FETCH/WRITE
// blowup per R2 -- watch it). 3 barriers/half. Split-bf16 3-MFMA products,
// layouts verified R6 (absmax 9.8e-4).
// ---------------------------------------------------------------------------
__global__ __launch_bounds__(256, 4) void lsh_attn_kernel(
    const float* __restrict__ qk, const float* __restrict__ v,
    const int* __restrict__ st, float* __restrict__ Obuf, float* __restrict__ Dbuf)
{
    __shared__ short Khi[64 * SB], Klo[64 * SB];   // double as Phi/Plo after dots
    __shared__ short Vhi[64 * SB], Vlo[64 * SB];   // transposed: [dim][key]
    __shared__ int   tk[64];

    short* Phi = Khi;
    short* Plo = Klo;

    int tid  = threadIdx.x;
    int lane = tid & 63;
    int w    = tid >> 6;          // wave id = query-strip / V key-group
    int quad = lane >> 4;
    int l15  = lane & 15;

    int bc = blockIdx.x;
    int b = bc >> 9, c = bc & (NCHUNK - 1);
    int cm = (c + NCHUNK - 1) & (NCHUNK - 1);

    const int*   stb = st + (size_t)b * (NHASH * SEQ);
    const float* qkb = qk + (size_t)b * SEQ * DIM;
    const float* vb  = v  + (size_t)b * SEQ * DIM;

    // ---- Q fragments in registers (both halves use the same Q) ----
    short8 qH[2], qL[2];
    {
        int qt = stb[c * 64 + 16 * w + l15];       // this lane's Q row token
        const float* qp = qkb + (size_t)qt * DIM + 8 * quad;
        float xs[8];
#pragma unroll
        for (int kb = 0; kb < 2; ++kb) {
            *(float4*)&xs[0] = *(const float4*)(qp + 32 * kb);
            *(float4*)&xs[4] = *(const float4*)(qp + 32 * kb + 4);
            split8_frag(xs, &qH[kb], &qL[kb]);
        }
    }
    // mask row-ids for this lane's C-fragment rows (quad*4+r), both halves
    int tqr[4];
#pragma unroll
    for (int r = 0; r < 4; ++r) tqr[r] = stb[c * 64 + 16 * w + quad * 4 + r];

    float   Dacc[4] = {0.f, 0.f, 0.f, 0.f};
    floatx4 oacc[4];
#pragma unroll
    for (int a = 0; a < 4; ++a) oacc[a] = (floatx4){0.f, 0.f, 0.f, 0.f};

    for (int half = 0; half < 2; ++half) {
        int ck = half ? cm : c;
        __syncthreads();              // prev-half P/V LDS reads complete

        {   // stage K (L2-normalized) split: 4 threads/row, 16 dims each
            int r = tid >> 2, s = tid & 3;
            int trow = stb[ck * 64 + r];
            if (s == 0) tk[r] = trow;
            const float4* k4 = (const float4*)(qkb + (size_t)trow * DIM + s * 16);
            float xs[16];
            *(float4*)&xs[0]  = k4[0];
            *(float4*)&xs[4]  = k4[1];
            *(float4*)&xs[8]  = k4[2];
            *(float4*)&xs[12] = k4[3];
            float ss = 0.f;
#pragma unroll
            for (int u = 0; u < 16; ++u) ss += xs[u] * xs[u];
            ss += __shfl_xor(ss, 1);
            ss += __shfl_xor(ss, 2);
            float sc = 1.0f / fmaxf(sqrtf(ss), 1e-12f);
#pragma unroll
            for (int u = 0; u < 16; ++u) xs[u] *= sc;
            split16_store(xs, &Khi[r * SB + s * 16], &Klo[r * SB + s * 16]);
        }
        {   // stage V TRANSPOSED split: thread = dim lane, keys w*16..w*16+15
            float xs[16];
#pragma unroll
            for (int u = 0; u < 16; ++u) {
                int trow = stb[ck * 64 + w * 16 + u];     // wave-uniform
                xs[u] = vb[(size_t)trow * DIM + lane];    // coalesced 256B row
            }
            split16_store(xs, &Vhi[lane * SB + w * 16], &Vlo[lane * SB + w * 16]);
        }
        __syncthreads();              // K, Vt, tk staged

        // dots: D = Q·K^T over 4 key-tiles, K=64 = 2 k-blocks, 3-term split
        floatx4 dt[4];
#pragma unroll
        for (int jt = 0; jt < 4; ++jt) dt[jt] = (floatx4){0.f, 0.f, 0.f, 0.f};
#pragma unroll
        for (int kb = 0; kb < 2; ++kb) {
#pragma unroll
            for (int jt = 0; jt < 4; ++jt) {
                short8 bH = *(const short8*)&Khi[(16 * jt + l15) * SB + kb * 32 + quad * 8];
                short8 bL = *(const short8*)&Klo[(16 * jt + l15) * SB + kb * 32 + quad * 8];
                dt[jt] = __builtin_amdgcn_mfma_f32_16x16x32_bf16(qH[kb], bH, dt[jt], 0, 0, 0);
                dt[jt] = __builtin_amdgcn_mfma_f32_16x16x32_bf16(qL[kb], bH, dt[jt], 0, 0, 0);
                dt[jt] = __builtin_amdgcn_mfma_f32_16x16x32_bf16(qH[kb], bL, dt[jt], 0, 0, 0);
            }
        }
        __syncthreads();              // all dots reads of K done -> P may overwrite

        // mask + exp (fp32) + wave-private P split-write + denominator partials
#pragma unroll
        for (int jt = 0; jt < 4; ++jt) {
            int tkc = tk[16 * jt + l15];
#pragma unroll
            for (int r = 0; r < 4; ++r) {
                float p = (tqr[r] == tkc) ? 0.f : __expf(dt[jt][r] * 0.125f);
                Dacc[r] += p;
                int idx = (16 * w + quad * 4 + r) * SB + 16 * jt + l15;
                Phi[idx] = (short)(__float_as_uint(p) >> 16);
                Plo[idx] = (short)(__float_as_uint(p - trunc_hi(p)) >> 16);
            }
        }

        // PV: O += P·V (A = own P strip -> no barrier; B = Vt)
#pragma unroll
        for (int kb = 0; kb < 2; ++kb) {
            short8 aH = *(const short8*)&Phi[(16 * w + l15) * SB + kb * 32 + quad * 8];
            short8 aL = *(const short8*)&Plo[(16 * w + l15) * SB + kb * 32 + quad * 8];
#pragma unroll
            for (int a = 0; a < 4; ++a) {
                short8 bH = *(const short8*)&Vhi[(16 * a + l15) * SB + kb * 32 + quad * 8];
                short8 bL = *(const short8*)&Vlo[(16 * a + l15) * SB + kb * 32 + quad * 8];
                oacc[a] = __builtin_amdgcn_mfma_f32_16x16x32_bf16(aH, bH, oacc[a], 0, 0, 0);
                oacc[a] = __builtin_amdgcn_mfma_f32_16x16x32_bf16(aL, bH, oacc[a], 0, 0, 0);
                oacc[a] = __builtin_amdgcn_mfma_f32_16x16x32_bf16(aH, bL, oacc[a], 0, 0, 0);
            }
        }
    }

    // epilogue: contention-free per-hash rows. oacc: row=quad*4+r, col=l15.
    size_t base = (size_t)b * (NHASH * SEQ) + (size_t)c * 64;
#pragma unroll
    for (int a = 0; a < 4; ++a)
#pragma unroll
        for (int r = 0; r < 4; ++r)
            Obuf[(base + 16 * w + quad * 4 + r) * DIM + 16 * a + l15] = oacc[a][r];
#pragma unroll
    for (int r = 0; r < 4; ++r) {
        float rs = Dacc[r];
        rs += __shfl_xor(rs, 1);
        rs += __shfl_xor(rs, 2);
        rs += __shfl_xor(rs, 4);
        rs += __shfl_xor(rs, 8);
        if (l15 == 0) Dbuf[base + 16 * w + quad * 4 + r] = rs;
    }
}

// ---------------------------------------------------------------------------
// Kernel 4: out[b,t] = sum_h O_h[inv_h(t)] / sum_h D_h[inv_h(t)].
// ---------------------------------------------------------------------------
__global__ __launch_bounds__(256) void lsh_combine_direct(
    const float* __restrict__ Obuf, const float* __restrict__ Dbuf,
    const int* __restrict__ inv, float* __restrict__ out)
{
    int gid = blockIdx.x * 256 + threadIdx.x;   // b*65536 + t*16 + d4
    int d4 = gid & 15;
    int t  = (gid >> 4) & (SEQ - 1);
    int b  = gid >> 16;

    float4 n = make_float4(0.f, 0.f, 0.f, 0.f);
    float den = 0.f;
#pragma unroll
    for (int h = 0; h < NHASH; ++h) {
        int bh = b * NHASH + h;
        int pos = inv[((size_t)bh << 12) + t];
        size_t row = ((size_t)bh << 12) + pos;
        float4 o = ((const float4*)Obuf)[row * 16 + d4];
        den += Dbuf[row];
        n.x += o.x; n.y += o.y; n.z += o.z; n.w += o.w;
    }
    float invd = 1.0f / den;
    float4 r; r.x = n.x*invd; r.y = n.y*invd; r.z = n.z*invd; r.w = n.w*invd;
    ((float4*)out)[gid] = r;
}

extern "C" void kernel_launch(void* const* d_in, const int* in_sizes, int n_in,
                              void* d_out, int out_size, void* d_ws, size_t ws_size,
                              hipStream_t stream)
{
    const float* qk  = (const float*)d_in[0];
    const float* v   = (const float*)d_in[1];
    const float* rot = (const float*)d_in[2];
    float* out = (float*)d_out;

    char* w = (char*)d_ws;
    // workspace layout (142.6 MB):
    //   [0, 2MB)        buckets : int[16*8*4096]
    //   [2, 4MB)        st      : int[16*8*4096]
    //   [4, 6MB)        inv     : int[16*8*4096]
    //   [6MB, +134.2MB) Obuf    : fp32[16*8*4096*64]
    //   then            Dbuf    : fp32[16*8*4096]
    int*   buckets = (int*)(w);
    int*   st      = (int*)(w + 2097152);
    int*   inv     = (int*)(w + 4194304);
    float* Obuf    = (float*)(w + 6291456);
    float* Dbuf    = (float*)(w + 6291456 + 134217728);

    lsh_hash_kernel<<<512, 256, 0, stream>>>(qk, rot, buckets);
    lsh_sort_kernel<<<128, 64, 0, stream>>>(buckets, st, inv);
    lsh_attn_kernel<<<8192, 256, 0, stream>>>(qk, v, st, Obuf, Dbuf);
    lsh_combine_direct<<<4096, 256, 0, stream>>>(Obuf, Dbuf, inv, out);
}

// Round 8
// 325.447 us; speedup vs baseline: 7.5049x; 1.0140x over previous
//
#include <hip/hip_runtime.h>

#define BATCH  16
#define SEQ    4096
#define DIM    64
#define NHASH  8
#define NCHUNK 512   // chunks per batch row (NHASH * SEQ / 64)
#define SB     72    // bf16 LDS row stride: 72*2=144 B, 16B-aligned for b128

typedef __attribute__((ext_vector_type(8))) short short8;   // 8 bf16 (4 VGPR)
typedef __attribute__((ext_vector_type(4))) float floatx4;  // MFMA C/D

__device__ __forceinline__ float trunc_hi(float a) {
    return __uint_as_float(__float_as_uint(a) & 0xffff0000u);
}
__device__ __forceinline__ unsigned pack_hi2(float a, float b) {
    return (__float_as_uint(a) >> 16) | (__float_as_uint(b) & 0xffff0000u);
}
// split 16 fp32 -> 16 bf16 hi + 16 bf16 lo (truncation split: x = hi + lo +
// O(2^-14 x)); store as 2x uint4 each (dst element offsets 16B-aligned).
__device__ __forceinline__ void split16_store(const float* xs, short* hiDst, short* loDst) {
    unsigned hd[8], ld[8];
#pragma unroll
    for (int u = 0; u < 8; ++u) {
        float a = xs[2*u], b = xs[2*u + 1];
        hd[u] = pack_hi2(a, b);
        ld[u] = pack_hi2(a - trunc_hi(a), b - trunc_hi(b));
    }
    *(uint4*)(hiDst)     = make_uint4(hd[0], hd[1], hd[2], hd[3]);
    *(uint4*)(hiDst + 8) = make_uint4(hd[4], hd[5], hd[6], hd[7]);
    *(uint4*)(loDst)     = make_uint4(ld[0], ld[1], ld[2], ld[3]);
    *(uint4*)(loDst + 8) = make_uint4(ld[4], ld[5], ld[6], ld[7]);
}
// split 8 fp32 -> bf16 hi/lo short8 fragments in registers
__device__ __forceinline__ void split8_frag(const float* xs, short8* hi, short8* lo) {
    union { unsigned u[4]; short8 s; } H, L;
#pragma unroll
    for (int u = 0; u < 4; ++u) {
        float a = xs[2*u], b = xs[2*u + 1];
        H.u[u] = pack_hi2(a, b);
        L.u[u] = pack_hi2(a - trunc_hi(a), b - trunc_hi(b));
    }
    *hi = H.s; *lo = L.s;
}

// ---------------------------------------------------------------------------
// Kernel 1: LSH hashing. R7 profiled 130 us at Occupancy 22% / VALU 13.5% --
// latency-bound at 2 blocks/CU (grid 512). Now 2 blocks per 128-token tile
// (grid 1024, 4 blocks/CU): block bit0 selects h-half; each thread computes
// 2 hashes. tt = tid&127, hg = tid>>7 (wave-uniform -> rot reads scalar).
// argmax first-max-wins like jnp. qk read twice total (+3 us, worth 2x TLP).
// ---------------------------------------------------------------------------
__global__ __launch_bounds__(256) void lsh_hash_kernel(
    const float* __restrict__ qk, const float* __restrict__ rot,
    int* __restrict__ buckets)
{
    __shared__ float qs[DIM * 128];
    int tid = threadIdx.x;
    int tt = tid & 127;
    int hg = tid >> 7;                     // 0/1, wave-uniform
    int tb   = blockIdx.x >> 1;
    int hsel = blockIdx.x & 1;
    int gid = tb * 128 + tt;               // b*4096 + t
    int b = gid >> 12, t = gid & 4095;

    const float4* src = (const float4*)(qk + (size_t)gid * DIM + hg * 32);
#pragma unroll
    for (int u = 0; u < 8; ++u) {
        float4 x = src[u];
        int f = hg * 32 + 4 * u;
        qs[(f + 0) * 128 + tt] = x.x;
        qs[(f + 1) * 128 + tt] = x.y;
        qs[(f + 2) * 128 + tt] = x.z;
        qs[(f + 3) * 128 + tt] = x.w;
    }
    __syncthreads();

    for (int h0 = 0; h0 < 2; ++h0) {
        int h = hsel * 4 + hg * 2 + h0;    // wave-uniform
        float acc[32];
#pragma unroll
        for (int i = 0; i < 32; ++i) acc[i] = 0.f;
        for (int f = 0; f < DIM; ++f) {
            float qf = qs[f * 128 + tt];
            const float* rp = rot + (f * NHASH + h) * 32;   // wave-uniform addr
#pragma unroll
            for (int i = 0; i < 32; ++i) acc[i] = fmaf(qf, rp[i], acc[i]);
        }
        float best = acc[0]; int bi = 0;
#pragma unroll
        for (int i = 1; i < 32; ++i) { if (acc[i] > best) { best = acc[i]; bi = i; } }
#pragma unroll
        for (int i = 0; i < 32; ++i) { float nv = -acc[i]; if (nv > best) { best = nv; bi = i + 32; } }
        buckets[((size_t)b * NHASH + h) * SEQ + t] = bi;
    }
}

// ---------------------------------------------------------------------------
// Kernel 2: stable counting sort per (b,h). One wave per block. Lane l owns
// tokens [64l, 64l+64) (contiguous -> stability). st[pos] = original token.
// (inv no longer needed: attn scatters straight to token-major layout.)
// ---------------------------------------------------------------------------
__global__ __launch_bounds__(64) void lsh_sort_kernel(
    const int* __restrict__ buckets, int* __restrict__ st)
{
    int bh = blockIdx.x;
    int lane = threadIdx.x;
    const int* bp = buckets + (size_t)bh * SEQ;
    __shared__ int hist[64 * 64];
    __shared__ int tot[64];
    __shared__ int base[64];

    for (int i = 0; i < 64; ++i) hist[(lane << 6) + i] = 0;
    __syncthreads();
    for (int u = 0; u < 64; ++u) {
        int tt = (lane << 6) + u;
        hist[(lane << 6) + bp[tt]] += 1;
    }
    __syncthreads();
    {
        int run = 0;
        for (int l = 0; l < 64; ++l) {
            int idx = (l << 6) + lane;
            int c0 = hist[idx];
            hist[idx] = run;
            run += c0;
        }
        tot[lane] = run;
    }
    __syncthreads();
    if (lane == 0) {
        int r = 0;
        for (int i = 0; i < 64; ++i) { base[i] = r; r += tot[i]; }
    }
    __syncthreads();
    int* op = st + (size_t)bh * SEQ;
    for (int u = 0; u < 64; ++u) {
        int tt = (lane << 6) + u;
        int bb = bp[tt];
        int idx = (lane << 6) + bb;
        int pos = base[bb] + hist[idx];
        hist[idx] = pos - base[bb] + 1;
        op[pos] = tt;
    }
}

// ---------------------------------------------------------------------------
// Kernel 3: MFMA attention (core unchanged from R7: split-bf16 3-MFMA
// products, Q frags in registers, P aliases K, 37 KB LDS -> 4 blocks/CU).
// EPILOGUE CHANGE: scatter O rows / denominators directly to TOKEN-MAJOR
// layout O[(b*4096+t)*8 + h], h = c>>6. Each 256 B row is written once
// (write-and-forget); this converts the combine kernel's latency-bound
// random GATHER (R7's 30 ms replay anomaly / dependent-chain inv->row->O)
// into streaming reads. No atomics anywhere.
// ---------------------------------------------------------------------------
__global__ __launch_bounds__(256, 4) void lsh_attn_kernel(
    const float* __restrict__ qk, const float* __restrict__ v,
    const int* __restrict__ st, float* __restrict__ Obuf, float* __restrict__ Dbuf)
{
    __shared__ short Khi[64 * SB], Klo[64 * SB];   // double as Phi/Plo after dots
    __shared__ short Vhi[64 * SB], Vlo[64 * SB];   // transposed: [dim][key]
    __shared__ int   tk[64];

    short* Phi = Khi;
    short* Plo = Klo;

    int tid  = threadIdx.x;
    int lane = tid & 63;
    int w    = tid >> 6;          // wave id = query-strip / V key-group
    int quad = lane >> 4;
    int l15  = lane & 15;

    int bc = blockIdx.x;
    int b = bc >> 9, c = bc & (NCHUNK - 1);
    int cm = (c + NCHUNK - 1) & (NCHUNK - 1);

    const int*   stb = st + (size_t)b * (NHASH * SEQ);
    const float* qkb = qk + (size_t)b * SEQ * DIM;
    const float* vb  = v  + (size_t)b * SEQ * DIM;

    // ---- Q fragments in registers (both halves use the same Q) ----
    short8 qH[2], qL[2];
    {
        int qt = stb[c * 64 + 16 * w + l15];       // this lane's Q row token
        const float* qp = qkb + (size_t)qt * DIM + 8 * quad;
        float xs[8];
#pragma unroll
        for (int kb = 0; kb < 2; ++kb) {
            *(float4*)&xs[0] = *(const float4*)(qp + 32 * kb);
            *(float4*)&xs[4] = *(const float4*)(qp + 32 * kb + 4);
            split8_frag(xs, &qH[kb], &qL[kb]);
        }
    }
    // mask row-ids for this lane's C-fragment rows (quad*4+r), both halves
    int tqr[4];
#pragma unroll
    for (int r = 0; r < 4; ++r) tqr[r] = stb[c * 64 + 16 * w + quad * 4 + r];

    float   Dacc[4] = {0.f, 0.f, 0.f, 0.f};
    floatx4 oacc[4];
#pragma unroll
    for (int a = 0; a < 4; ++a) oacc[a] = (floatx4){0.f, 0.f, 0.f, 0.f};

    for (int half = 0; half < 2; ++half) {
        int ck = half ? cm : c;
        __syncthreads();              // prev-half P/V LDS reads complete

        {   // stage K (L2-normalized) split: 4 threads/row, 16 dims each
            int r = tid >> 2, s = tid & 3;
            int trow = stb[ck * 64 + r];
            if (s == 0) tk[r] = trow;
            const float4* k4 = (const float4*)(qkb + (size_t)trow * DIM + s * 16);
            float xs[16];
            *(float4*)&xs[0]  = k4[0];
            *(float4*)&xs[4]  = k4[1];
            *(float4*)&xs[8]  = k4[2];
            *(float4*)&xs[12] = k4[3];
            float ss = 0.f;
#pragma unroll
            for (int u = 0; u < 16; ++u) ss += xs[u] * xs[u];
            ss += __shfl_xor(ss, 1);
            ss += __shfl_xor(ss, 2);
            float sc = 1.0f / fmaxf(sqrtf(ss), 1e-12f);
#pragma unroll
            for (int u = 0; u < 16; ++u) xs[u] *= sc;
            split16_store(xs, &Khi[r * SB + s * 16], &Klo[r * SB + s * 16]);
        }
        {   // stage V TRANSPOSED split: thread = dim lane, keys w*16..w*16+15
            float xs[16];
#pragma unroll
            for (int u = 0; u < 16; ++u) {
                int trow = stb[ck * 64 + w * 16 + u];     // wave-uniform
                xs[u] = vb[(size_t)trow * DIM + lane];    // coalesced 256B row
            }
            split16_store(xs, &Vhi[lane * SB + w * 16], &Vlo[lane * SB + w * 16]);
        }
        __syncthreads();              // K, Vt, tk staged

        // dots: D = Q·K^T over 4 key-tiles, K=64 = 2 k-blocks, 3-term split
        floatx4 dt[4];
#pragma unroll
        for (int jt = 0; jt < 4; ++jt) dt[jt] = (floatx4){0.f, 0.f, 0.f, 0.f};
#pragma unroll
        for (int kb = 0; kb < 2; ++kb) {
#pragma unroll
            for (int jt = 0; jt < 4; ++jt) {
                short8 bH = *(const short8*)&Khi[(16 * jt + l15) * SB + kb * 32 + quad * 8];
                short8 bL = *(const short8*)&Klo[(16 * jt + l15) * SB + kb * 32 + quad * 8];
                dt[jt] = __builtin_amdgcn_mfma_f32_16x16x32_bf16(qH[kb], bH, dt[jt], 0, 0, 0);
                dt[jt] = __builtin_amdgcn_mfma_f32_16x16x32_bf16(qL[kb], bH, dt[jt], 0, 0, 0);
                dt[jt] = __builtin_amdgcn_mfma_f32_16x16x32_bf16(qH[kb], bL, dt[jt], 0, 0, 0);
            }
        }
        __syncthreads();              // all dots reads of K done -> P may overwrite

        // mask + exp (fp32) + wave-private P split-write + denominator partials
#pragma unroll
        for (int jt = 0; jt < 4; ++jt) {
            int tkc = tk[16 * jt + l15];
#pragma unroll
            for (int r = 0; r < 4; ++r) {
                float p = (tqr[r] == tkc) ? 0.f : __expf(dt[jt][r] * 0.125f);
                Dacc[r] += p;
                int idx = (16 * w + quad * 4 + r) * SB + 16 * jt + l15;
                Phi[idx] = (short)(__float_as_uint(p) >> 16);
                Plo[idx] = (short)(__float_as_uint(p - trunc_hi(p)) >> 16);
            }
        }

        // PV: O += P·V (A = own P strip -> no barrier; B = Vt)
#pragma unroll
        for (int kb = 0; kb < 2; ++kb) {
            short8 aH = *(const short8*)&Phi[(16 * w + l15) * SB + kb * 32 + quad * 8];
            short8 aL = *(const short8*)&Plo[(16 * w + l15) * SB + kb * 32 + quad * 8];
#pragma unroll
            for (int a = 0; a < 4; ++a) {
                short8 bH = *(const short8*)&Vhi[(16 * a + l15) * SB + kb * 32 + quad * 8];
                short8 bL = *(const short8*)&Vlo[(16 * a + l15) * SB + kb * 32 + quad * 8];
                oacc[a] = __builtin_amdgcn_mfma_f32_16x16x32_bf16(aH, bH, oacc[a], 0, 0, 0);
                oacc[a] = __builtin_amdgcn_mfma_f32_16x16x32_bf16(aL, bH, oacc[a], 0, 0, 0);
                oacc[a] = __builtin_amdgcn_mfma_f32_16x16x32_bf16(aH, bL, oacc[a], 0, 0, 0);
            }
        }
    }

    // epilogue: scatter to token-major rows O[(b*4096+t)*8 + h][64], h = c>>6.
    // oacc: row = quad*4+r (query in strip), col = l15 (dim in d-tile a).
    // Each (t,h) O row = 256 B written entirely by one quad-group (4 a-tiles
    // of 64 B each) -> full-line writes, no contention.
    int h = c >> 6;
#pragma unroll
    for (int r = 0; r < 4; ++r) {
        int t = tqr[r];
        size_t rowb = ((size_t)(b * SEQ + t) * NHASH + h) * DIM;
#pragma unroll
        for (int a = 0; a < 4; ++a)
            Obuf[rowb + 16 * a + l15] = oacc[a][r];
    }
#pragma unroll
    for (int r = 0; r < 4; ++r) {
        float rs = Dacc[r];
        rs += __shfl_xor(rs, 1);
        rs += __shfl_xor(rs, 2);
        rs += __shfl_xor(rs, 4);
        rs += __shfl_xor(rs, 8);
        if (l15 == 0) Dbuf[(size_t)(b * SEQ + tqr[r]) * NHASH + h] = rs;
    }
}

// ---------------------------------------------------------------------------
// Kernel 4: out[b,t] = sum_h O[(b,t),h] / sum_h D[(b,t),h] -- fully
// streaming: per token 8x256 B contiguous O + 32 B D, all independent loads.
// ---------------------------------------------------------------------------
__global__ __launch_bounds__(256) void lsh_combine_tok(
    const float* __restrict__ Obuf, const float* __restrict__ Dbuf,
    float* __restrict__ out)
{
    int gid = blockIdx.x * 256 + threadIdx.x;   // (b*4096+t)*16 + d4
    int d4 = gid & 15;
    int bt = gid >> 4;

    const float4* op = (const float4*)Obuf + (size_t)bt * (NHASH * 16);
    const float*  dp = Dbuf + (size_t)bt * NHASH;

    float4 n = make_float4(0.f, 0.f, 0.f, 0.f);
    float den = 0.f;
#pragma unroll
    for (int h = 0; h < NHASH; ++h) {
        float4 o = op[h * 16 + d4];
        den += dp[h];
        n.x += o.x; n.y += o.y; n.z += o.z; n.w += o.w;
    }
    float invd = 1.0f / den;
    float4 r; r.x = n.x*invd; r.y = n.y*invd; r.z = n.z*invd; r.w = n.w*invd;
    ((float4*)out)[gid] = r;
}

extern "C" void kernel_launch(void* const* d_in, const int* in_sizes, int n_in,
                              void* d_out, int out_size, void* d_ws, size_t ws_size,
                              hipStream_t stream)
{
    const float* qk  = (const float*)d_in[0];
    const float* v   = (const float*)d_in[1];
    const float* rot = (const float*)d_in[2];
    float* out = (float*)d_out;

    char* w = (char*)d_ws;
    // workspace layout (140.5 MB):
    //   [0, 2MB)        buckets : int[16*8*4096]
    //   [2, 4MB)        st      : int[16*8*4096]
    //   [4MB, +134.2MB) Obuf    : fp32[16*4096*8*64]  (token-major, h inner)
    //   then            Dbuf    : fp32[16*4096*8]
    int*   buckets = (int*)(w);
    int*   st      = (int*)(w + 2097152);
    float* Obuf    = (float*)(w + 4194304);
    float* Dbuf    = (float*)(w + 4194304 + 134217728);

    lsh_hash_kernel<<<1024, 256, 0, stream>>>(qk, rot, buckets);
    lsh_sort_kernel<<<128, 64, 0, stream>>>(buckets, st);
    lsh_attn_kernel<<<8192, 256, 0, stream>>>(qk, v, st, Obuf, Dbuf);
    lsh_combine_tok<<<4096, 256, 0, stream>>>(Obuf, Dbuf, out);
}

// Round 9
// 244.905 us; speedup vs baseline: 9.9731x; 1.3289x over previous
//
#include <hip/hip_runtime.h>

#define BATCH  16
#define SEQ    4096
#define DIM    64
#define NHASH  8
#define NCHUNK 512   // chunks per batch row (NHASH * SEQ / 64)
#define SB     72    // bf16 LDS row stride: 72*2=144 B, 16B-aligned for b128

typedef __attribute__((ext_vector_type(8))) short short8;   // 8 bf16 (4 VGPR)
typedef __attribute__((ext_vector_type(4))) float floatx4;  // MFMA C/D

__device__ __forceinline__ float trunc_hi(float a) {
    return __uint_as_float(__float_as_uint(a) & 0xffff0000u);
}
__device__ __forceinline__ unsigned pack_hi2(float a, float b) {
    return (__float_as_uint(a) >> 16) | (__float_as_uint(b) & 0xffff0000u);
}
// split 16 fp32 -> 16 bf16 hi + 16 bf16 lo (truncation split: x = hi + lo +
// O(2^-14 x)); store as 2x uint4 each (dst element offsets 16B-aligned).
__device__ __forceinline__ void split16_store(const float* xs, short* hiDst, short* loDst) {
    unsigned hd[8], ld[8];
#pragma unroll
    for (int u = 0; u < 8; ++u) {
        float a = xs[2*u], b = xs[2*u + 1];
        hd[u] = pack_hi2(a, b);
        ld[u] = pack_hi2(a - trunc_hi(a), b - trunc_hi(b));
    }
    *(uint4*)(hiDst)     = make_uint4(hd[0], hd[1], hd[2], hd[3]);
    *(uint4*)(hiDst + 8) = make_uint4(hd[4], hd[5], hd[6], hd[7]);
    *(uint4*)(loDst)     = make_uint4(ld[0], ld[1], ld[2], ld[3]);
    *(uint4*)(loDst + 8) = make_uint4(ld[4], ld[5], ld[6], ld[7]);
}
// split 8 fp32 -> bf16 hi/lo short8 fragments in registers
__device__ __forceinline__ void split8_frag(const float* xs, short8* hi, short8* lo) {
    union { unsigned u[4]; short8 s; } H, L;
#pragma unroll
    for (int u = 0; u < 4; ++u) {
        float a = xs[2*u], b = xs[2*u + 1];
        H.u[u] = pack_hi2(a, b);
        L.u[u] = pack_hi2(a - trunc_hi(a), b - trunc_hi(b));
    }
    *hi = H.s; *lo = L.s;
}

// ---------------------------------------------------------------------------
// Kernel 1: LSH hashing, SMEM-free rewrite. R8 post-mortem: occupancy 2x'd
// but dur/VALUBusy froze at 127 us/14% -- the f-loop's per-iteration
// s_load_dwordx16 (rot row) + ds_read share one lgkmcnt and drain with
// s_waitcnt lgkmcnt(0) before each FMA block: a serial ~300cyc/iter chain
// identical in every wave (TLP can't hide it). Now: rot slice (4 h x 64 f x
// 32 i = 32 KB) staged to LDS ONCE per block via coalesced vector loads;
// q rows in 32 B register tiles from global (L1-hot on h' reuse); inner loop
// = broadcast ds_read_b128 (all lanes same addr, conflict-free) + dense FMA,
// statically unrolled. Block = 128 tokens x 4 hashes; thread (tt=tid&127,
// hh=tid>>7) does h' in {2hh, 2hh+1} (wave-uniform). argmax first-max-wins.
// ---------------------------------------------------------------------------
__global__ __launch_bounds__(256) void lsh_hash_kernel(
    const float* __restrict__ qk, const float* __restrict__ rot,
    int* __restrict__ buckets)
{
    __shared__ float rs[64 * 128];     // [f][h'][i] = f*128 + h'*32 + i (32 KB)
    int tid = threadIdx.x;
    int tb   = blockIdx.x >> 1;        // 128-token tile
    int hsel = blockIdx.x & 1;         // h half: h = hsel*4 + h'

    {   // stage rot slice: 2048 float4, 8 per thread, coalesced 512B segments
        const float4* rg = (const float4*)rot;
#pragma unroll
        for (int j = 0; j < 8; ++j) {
            int idx4 = j * 256 + tid;          // 0..2047 over (f, h', i4)
            int f = idx4 >> 5, r4 = idx4 & 31;
            ((float4*)rs)[idx4] = rg[f * 64 + hsel * 32 + r4];
        }
    }
    __syncthreads();

    int tt = tid & 127;
    int hh = tid >> 7;                 // 0/1, wave-uniform
    int gid = tb * 128 + tt;           // b*4096 + t
    int b = gid >> 12, t = gid & 4095;
    const float* qrow = qk + (size_t)gid * DIM;

#pragma unroll
    for (int h0 = 0; h0 < 2; ++h0) {
        int hp = hh * 2 + h0;          // h' in 0..3, wave-uniform
        const float* rbase = rs + hp * 32;
        float acc[32];
#pragma unroll
        for (int i = 0; i < 32; ++i) acc[i] = 0.f;
#pragma unroll 2
        for (int ft = 0; ft < 8; ++ft) {
            float q8[8];
            *(float4*)&q8[0] = *(const float4*)(qrow + ft * 8);
            *(float4*)&q8[4] = *(const float4*)(qrow + ft * 8 + 4);
#pragma unroll
            for (int f8 = 0; f8 < 8; ++f8) {
                float qf = q8[f8];
                const float* rp = rbase + (ft * 8 + f8) * 128;  // static offs
#pragma unroll
                for (int i = 0; i < 32; ++i)
                    acc[i] = fmaf(qf, rp[i], acc[i]);
            }
        }
        float best = acc[0]; int bi = 0;
#pragma unroll
        for (int i = 1; i < 32; ++i) { if (acc[i] > best) { best = acc[i]; bi = i; } }
#pragma unroll
        for (int i = 0; i < 32; ++i) { float nv = -acc[i]; if (nv > best) { best = nv; bi = i + 32; } }
        int h = hsel * 4 + hp;
        buckets[((size_t)b * NHASH + h) * SEQ + t] = bi;
    }
}

// ---------------------------------------------------------------------------
// Kernel 2: stable counting sort per (b,h). One wave per block. Lane l owns
// tokens [64l, 64l+64) (contiguous -> stability). st[pos] = original token.
// ---------------------------------------------------------------------------
__global__ __launch_bounds__(64) void lsh_sort_kernel(
    const int* __restrict__ buckets, int* __restrict__ st)
{
    int bh = blockIdx.x;
    int lane = threadIdx.x;
    const int* bp = buckets + (size_t)bh * SEQ;
    __shared__ int hist[64 * 64];
    __shared__ int tot[64];
    __shared__ int base[64];

    for (int i = 0; i < 64; ++i) hist[(lane << 6) + i] = 0;
    __syncthreads();
    for (int u = 0; u < 64; ++u) {
        int tt = (lane << 6) + u;
        hist[(lane << 6) + bp[tt]] += 1;
    }
    __syncthreads();
    {
        int run = 0;
        for (int l = 0; l < 64; ++l) {
            int idx = (l << 6) + lane;
            int c0 = hist[idx];
            hist[idx] = run;
            run += c0;
        }
        tot[lane] = run;
    }
    __syncthreads();
    if (lane == 0) {
        int r = 0;
        for (int i = 0; i < 64; ++i) { base[i] = r; r += tot[i]; }
    }
    __syncthreads();
    int* op = st + (size_t)bh * SEQ;
    for (int u = 0; u < 64; ++u) {
        int tt = (lane << 6) + u;
        int bb = bp[tt];
        int idx = (lane << 6) + bb;
        int pos = base[bb] + hist[idx];
        hist[idx] = pos - base[bb] + 1;
        op[pos] = tt;
    }
}

// ---------------------------------------------------------------------------
// Kernel 3: MFMA attention (unchanged from R8: split-bf16 3-MFMA products,
// Q frags in registers, P aliases K, 37 KB LDS -> 4 blocks/CU, token-major
// scatter epilogue, no atomics).
// ---------------------------------------------------------------------------
__global__ __launch_bounds__(256, 4) void lsh_attn_kernel(
    const float* __restrict__ qk, const float* __restrict__ v,
    const int* __restrict__ st, float* __restrict__ Obuf, float* __restrict__ Dbuf)
{
    __shared__ short Khi[64 * SB], Klo[64 * SB];   // double as Phi/Plo after dots
    __shared__ short Vhi[64 * SB], Vlo[64 * SB];   // transposed: [dim][key]
    __shared__ int   tk[64];

    short* Phi = Khi;
    short* Plo = Klo;

    int tid  = threadIdx.x;
    int lane = tid & 63;
    int w    = tid >> 6;          // wave id = query-strip / V key-group
    int quad = lane >> 4;
    int l15  = lane & 15;

    int bc = blockIdx.x;
    int b = bc >> 9, c = bc & (NCHUNK - 1);
    int cm = (c + NCHUNK - 1) & (NCHUNK - 1);

    const int*   stb = st + (size_t)b * (NHASH * SEQ);
    const float* qkb = qk + (size_t)b * SEQ * DIM;
    const float* vb  = v  + (size_t)b * SEQ * DIM;

    // ---- Q fragments in registers (both halves use the same Q) ----
    short8 qH[2], qL[2];
    {
        int qt = stb[c * 64 + 16 * w + l15];       // this lane's Q row token
        const float* qp = qkb + (size_t)qt * DIM + 8 * quad;
        float xs[8];
#pragma unroll
        for (int kb = 0; kb < 2; ++kb) {
            *(float4*)&xs[0] = *(const float4*)(qp + 32 * kb);
            *(float4*)&xs[4] = *(const float4*)(qp + 32 * kb + 4);
            split8_frag(xs, &qH[kb], &qL[kb]);
        }
    }
    // mask row-ids for this lane's C-fragment rows (quad*4+r), both halves
    int tqr[4];
#pragma unroll
    for (int r = 0; r < 4; ++r) tqr[r] = stb[c * 64 + 16 * w + quad * 4 + r];

    float   Dacc[4] = {0.f, 0.f, 0.f, 0.f};
    floatx4 oacc[4];
#pragma unroll
    for (int a = 0; a < 4; ++a) oacc[a] = (floatx4){0.f, 0.f, 0.f, 0.f};

    for (int half = 0; half < 2; ++half) {
        int ck = half ? cm : c;
        __syncthreads();              // prev-half P/V LDS reads complete

        {   // stage K (L2-normalized) split: 4 threads/row, 16 dims each
            int r = tid >> 2, s = tid & 3;
            int trow = stb[ck * 64 + r];
            if (s == 0) tk[r] = trow;
            const float4* k4 = (const float4*)(qkb + (size_t)trow * DIM + s * 16);
            float xs[16];
            *(float4*)&xs[0]  = k4[0];
            *(float4*)&xs[4]  = k4[1];
            *(float4*)&xs[8]  = k4[2];
            *(float4*)&xs[12] = k4[3];
            float ss = 0.f;
#pragma unroll
            for (int u = 0; u < 16; ++u) ss += xs[u] * xs[u];
            ss += __shfl_xor(ss, 1);
            ss += __shfl_xor(ss, 2);
            float sc = 1.0f / fmaxf(sqrtf(ss), 1e-12f);
#pragma unroll
            for (int u = 0; u < 16; ++u) xs[u] *= sc;
            split16_store(xs, &Khi[r * SB + s * 16], &Klo[r * SB + s * 16]);
        }
        {   // stage V TRANSPOSED split: thread = dim lane, keys w*16..w*16+15
            float xs[16];
#pragma unroll
            for (int u = 0; u < 16; ++u) {
                int trow = stb[ck * 64 + w * 16 + u];     // wave-uniform
                xs[u] = vb[(size_t)trow * DIM + lane];    // coalesced 256B row
            }
            split16_store(xs, &Vhi[lane * SB + w * 16], &Vlo[lane * SB + w * 16]);
        }
        __syncthreads();              // K, Vt, tk staged

        // dots: D = Q·K^T over 4 key-tiles, K=64 = 2 k-blocks, 3-term split
        floatx4 dt[4];
#pragma unroll
        for (int jt = 0; jt < 4; ++jt) dt[jt] = (floatx4){0.f, 0.f, 0.f, 0.f};
#pragma unroll
        for (int kb = 0; kb < 2; ++kb) {
#pragma unroll
            for (int jt = 0; jt < 4; ++jt) {
                short8 bH = *(const short8*)&Khi[(16 * jt + l15) * SB + kb * 32 + quad * 8];
                short8 bL = *(const short8*)&Klo[(16 * jt + l15) * SB + kb * 32 + quad * 8];
                dt[jt] = __builtin_amdgcn_mfma_f32_16x16x32_bf16(qH[kb], bH, dt[jt], 0, 0, 0);
                dt[jt] = __builtin_amdgcn_mfma_f32_16x16x32_bf16(qL[kb], bH, dt[jt], 0, 0, 0);
                dt[jt] = __builtin_amdgcn_mfma_f32_16x16x32_bf16(qH[kb], bL, dt[jt], 0, 0, 0);
            }
        }
        __syncthreads();              // all dots reads of K done -> P may overwrite

        // mask + exp (fp32) + wave-private P split-write + denominator partials
#pragma unroll
        for (int jt = 0; jt < 4; ++jt) {
            int tkc = tk[16 * jt + l15];
#pragma unroll
            for (int r = 0; r < 4; ++r) {
                float p = (tqr[r] == tkc) ? 0.f : __expf(dt[jt][r] * 0.125f);
                Dacc[r] += p;
                int idx = (16 * w + quad * 4 + r) * SB + 16 * jt + l15;
                Phi[idx] = (short)(__float_as_uint(p) >> 16);
                Plo[idx] = (short)(__float_as_uint(p - trunc_hi(p)) >> 16);
            }
        }

        // PV: O += P·V (A = own P strip -> no barrier; B = Vt)
#pragma unroll
        for (int kb = 0; kb < 2; ++kb) {
            short8 aH = *(const short8*)&Phi[(16 * w + l15) * SB + kb * 32 + quad * 8];
            short8 aL = *(const short8*)&Plo[(16 * w + l15) * SB + kb * 32 + quad * 8];
#pragma unroll
            for (int a = 0; a < 4; ++a) {
                short8 bH = *(const short8*)&Vhi[(16 * a + l15) * SB + kb * 32 + quad * 8];
                short8 bL = *(const short8*)&Vlo[(16 * a + l15) * SB + kb * 32 + quad * 8];
                oacc[a] = __builtin_amdgcn_mfma_f32_16x16x32_bf16(aH, bH, oacc[a], 0, 0, 0);
                oacc[a] = __builtin_amdgcn_mfma_f32_16x16x32_bf16(aL, bH, oacc[a], 0, 0, 0);
                oacc[a] = __builtin_amdgcn_mfma_f32_16x16x32_bf16(aH, bL, oacc[a], 0, 0, 0);
            }
        }
    }

    // epilogue: scatter to token-major rows O[(b*4096+t)*8 + h][64], h = c>>6.
    int h = c >> 6;
#pragma unroll
    for (int r = 0; r < 4; ++r) {
        int t = tqr[r];
        size_t rowb = ((size_t)(b * SEQ + t) * NHASH + h) * DIM;
#pragma unroll
        for (int a = 0; a < 4; ++a)
            Obuf[rowb + 16 * a + l15] = oacc[a][r];
    }
#pragma unroll
    for (int r = 0; r < 4; ++r) {
        float rs = Dacc[r];
        rs += __shfl_xor(rs, 1);
        rs += __shfl_xor(rs, 2);
        rs += __shfl_xor(rs, 4);
        rs += __shfl_xor(rs, 8);
        if (l15 == 0) Dbuf[(size_t)(b * SEQ + tqr[r]) * NHASH + h] = rs;
    }
}

// ---------------------------------------------------------------------------
// Kernel 4: out[b,t] = sum_h O[(b,t),h] / sum_h D[(b,t),h] -- fully
// streaming: per token 8x256 B contiguous O + 32 B D, all independent loads.
// ---------------------------------------------------------------------------
__global__ __launch_bounds__(256) void lsh_combine_tok(
    const float* __restrict__ Obuf, const float* __restrict__ Dbuf,
    float* __restrict__ out)
{
    int gid = blockIdx.x * 256 + threadIdx.x;   // (b*4096+t)*16 + d4
    int d4 = gid & 15;
    int bt = gid >> 4;

    const float4* op = (const float4*)Obuf + (size_t)bt * (NHASH * 16);
    const float*  dp = Dbuf + (size_t)bt * NHASH;

    float4 n = make_float4(0.f, 0.f, 0.f, 0.f);
    float den = 0.f;
#pragma unroll
    for (int h = 0; h < NHASH; ++h) {
        float4 o = op[h * 16 + d4];
        den += dp[h];
        n.x += o.x; n.y += o.y; n.z += o.z; n.w += o.w;
    }
    float invd = 1.0f / den;
    float4 r; r.x = n.x*invd; r.y = n.y*invd; r.z = n.z*invd; r.w = n.w*invd;
    ((float4*)out)[gid] = r;
}

extern "C" void kernel_launch(void* const* d_in, const int* in_sizes, int n_in,
                              void* d_out, int out_size, void* d_ws, size_t ws_size,
                              hipStream_t stream)
{
    const float* qk  = (const float*)d_in[0];
    const float* v   = (const float*)d_in[1];
    const float* rot = (const float*)d_in[2];
    float* out = (float*)d_out;

    char* w = (char*)d_ws;
    // workspace layout (140.5 MB):
    //   [0, 2MB)        buckets : int[16*8*4096]
    //   [2, 4MB)        st      : int[16*8*4096]
    //   [4MB, +134.2MB) Obuf    : fp32[16*4096*8*64]  (token-major, h inner)
    //   then            Dbuf    : fp32[16*4096*8]
    int*   buckets = (int*)(w);
    int*   st      = (int*)(w + 2097152);
    float* Obuf    = (float*)(w + 4194304);
    float* Dbuf    = (float*)(w + 4194304 + 134217728);

    lsh_hash_kernel<<<1024, 256, 0, stream>>>(qk, rot, buckets);
    lsh_sort_kernel<<<128, 64, 0, stream>>>(buckets, st);
    lsh_attn_kernel<<<8192, 256, 0, stream>>>(qk, v, st, Obuf, Dbuf);
    lsh_combine_tok<<<4096, 256, 0, stream>>>(Obuf, Dbuf, out);
}

// Round 10
// 244.229 us; speedup vs baseline: 10.0007x; 1.0028x over previous
//
#include <hip/hip_runtime.h>

#define BATCH  16
#define SEQ    4096
#define DIM    64
#define NHASH  8
#define NCHUNK 512   // chunks per batch row (NHASH * SEQ / 64)
#define SB     72    // bf16 LDS row stride: 72*2=144 B, 16B-aligned for b128

typedef __attribute__((ext_vector_type(8))) short short8;   // 8 bf16 (4 VGPR)
typedef __attribute__((ext_vector_type(4))) float floatx4;  // MFMA C/D

__device__ __forceinline__ float trunc_hi(float a) {
    return __uint_as_float(__float_as_uint(a) & 0xffff0000u);
}
__device__ __forceinline__ unsigned pack_hi2(float a, float b) {
    return (__float_as_uint(a) >> 16) | (__float_as_uint(b) & 0xffff0000u);
}
// split 16 fp32 -> 16 bf16 hi + 16 bf16 lo (truncation split: x = hi + lo +
// O(2^-14 x)); store as 2x uint4 each (dst element offsets 16B-aligned).
__device__ __forceinline__ void split16_store(const float* xs, short* hiDst, short* loDst) {
    unsigned hd[8], ld[8];
#pragma unroll
    for (int u = 0; u < 8; ++u) {
        float a = xs[2*u], b = xs[2*u + 1];
        hd[u] = pack_hi2(a, b);
        ld[u] = pack_hi2(a - trunc_hi(a), b - trunc_hi(b));
    }
    *(uint4*)(hiDst)     = make_uint4(hd[0], hd[1], hd[2], hd[3]);
    *(uint4*)(hiDst + 8) = make_uint4(hd[4], hd[5], hd[6], hd[7]);
    *(uint4*)(loDst)     = make_uint4(ld[0], ld[1], ld[2], ld[3]);
    *(uint4*)(loDst + 8) = make_uint4(ld[4], ld[5], ld[6], ld[7]);
}
// split 8 fp32 -> bf16 hi/lo short8 fragments in registers
__device__ __forceinline__ void split8_frag(const float* xs, short8* hi, short8* lo) {
    union { unsigned u[4]; short8 s; } H, L;
#pragma unroll
    for (int u = 0; u < 4; ++u) {
        float a = xs[2*u], b = xs[2*u + 1];
        H.u[u] = pack_hi2(a, b);
        L.u[u] = pack_hi2(a - trunc_hi(a), b - trunc_hi(b));
    }
    *hi = H.s; *lo = L.s;
}

// ---------------------------------------------------------------------------
// Kernel 1: LSH hashing, 2 tokens/thread. R9's structure issued 8 broadcast
// ds_read_b128 per 32 FMAs (1:4) -> LDS-pipe-bound. Same reads now feed two
// tokens' FMAs (1:8). Block = 256-token tile x 4 hashes (hsel); thread
// (tt=tid&127, hh=tid>>7) owns tokens {tt, tt+128} and h' in {2hh, 2hh+1}
// (wave-uniform -> rot LDS reads are same-address broadcasts, conflict-free).
// rot slice (4h' x 64f x 32i = 32 KB) staged once per block, coalesced.
// fp32 FMA throughout (argmax flips are catastrophic; bf16/MFMA is NOT safe
// here). launch_bounds(256,2): acc0+acc1=64 VGPR need headroom; grid 512 is
// 2 blocks/CU regardless. argmax first-max-wins like jnp.
// ---------------------------------------------------------------------------
__global__ __launch_bounds__(256, 2) void lsh_hash_kernel(
    const float* __restrict__ qk, const float* __restrict__ rot,
    int* __restrict__ buckets)
{
    __shared__ float rs[64 * 128];     // [f][h'][i] = f*128 + h'*32 + i (32 KB)
    int tid = threadIdx.x;
    int tb   = blockIdx.x >> 1;        // 256-token tile
    int hsel = blockIdx.x & 1;         // h half: h = hsel*4 + h'

    {   // stage rot slice: 2048 float4, 8 per thread, coalesced 512B segments
        const float4* rg = (const float4*)rot;
#pragma unroll
        for (int j = 0; j < 8; ++j) {
            int idx4 = j * 256 + tid;          // 0..2047 over (f, h', i4)
            int f = idx4 >> 5, r4 = idx4 & 31;
            ((float4*)rs)[idx4] = rg[f * 64 + hsel * 32 + r4];
        }
    }
    __syncthreads();

    int tt = tid & 127;
    int hh = tid >> 7;                 // 0/1, wave-uniform
    int gid0 = tb * 256 + tt;          // b*4096 + t (token 0)
    int gid1 = gid0 + 128;             // token 1 (same batch: 4096 % 256 == 0)
    const float* q0 = qk + (size_t)gid0 * DIM;
    const float* q1 = qk + (size_t)gid1 * DIM;

#pragma unroll
    for (int h0 = 0; h0 < 2; ++h0) {
        int hp = hh * 2 + h0;          // h' in 0..3, wave-uniform
        const float* rbase = rs + hp * 32;
        float a0[32], a1[32];
#pragma unroll
        for (int i = 0; i < 32; ++i) { a0[i] = 0.f; a1[i] = 0.f; }
#pragma unroll 1
        for (int ft = 0; ft < 8; ++ft) {
            float qa[8], qb[8];
            *(float4*)&qa[0] = *(const float4*)(q0 + ft * 8);
            *(float4*)&qa[4] = *(const float4*)(q0 + ft * 8 + 4);
            *(float4*)&qb[0] = *(const float4*)(q1 + ft * 8);
            *(float4*)&qb[4] = *(const float4*)(q1 + ft * 8 + 4);
#pragma unroll
            for (int f8 = 0; f8 < 8; ++f8) {
                const float* rp = rbase + (ft * 8 + f8) * 128;  // static offs
                float x = qa[f8], y = qb[f8];
#pragma unroll
                for (int i = 0; i < 32; ++i) {
                    float r = rp[i];
                    a0[i] = fmaf(x, r, a0[i]);
                    a1[i] = fmaf(y, r, a1[i]);
                }
            }
        }
        int h = hsel * 4 + hp;
        {
            float best = a0[0]; int bi = 0;
#pragma unroll
            for (int i = 1; i < 32; ++i) { if (a0[i] > best) { best = a0[i]; bi = i; } }
#pragma unroll
            for (int i = 0; i < 32; ++i) { float nv = -a0[i]; if (nv > best) { best = nv; bi = i + 32; } }
            int b = gid0 >> 12, t = gid0 & 4095;
            buckets[((size_t)b * NHASH + h) * SEQ + t] = bi;
        }
        {
            float best = a1[0]; int bi = 0;
#pragma unroll
            for (int i = 1; i < 32; ++i) { if (a1[i] > best) { best = a1[i]; bi = i; } }
#pragma unroll
            for (int i = 0; i < 32; ++i) { float nv = -a1[i]; if (nv > best) { best = nv; bi = i + 32; } }
            int b = gid1 >> 12, t = gid1 & 4095;
            buckets[((size_t)b * NHASH + h) * SEQ + t] = bi;
        }
    }
}

// ---------------------------------------------------------------------------
// Kernel 2: stable counting sort per (b,h), 4-wave parallel (R9 was one wave
// per block = 0.5 blocks/CU with 64-deep dependent LDS rmw chains). 256
// threads; thread tid owns tokens [tid*16, tid*16+16) (contiguous ->
// stability), buckets kept in registers (coalesced int4 loads). hist[256][65]
// (pad 65: bank = (tid+b)%32, spreads random-bucket collisions). Hierarchical
// prefix: per-wave 64-segment scan (bucket=lane, conflict-free 2-way) ->
// wave 0 cross-segment scan + 6-step shuffle scan for bucket bases.
// pos = base[b] + seg[w][b] + intra-segment prefix + local count.
// ---------------------------------------------------------------------------
__global__ __launch_bounds__(256) void lsh_sort_kernel(
    const int* __restrict__ buckets, int* __restrict__ st)
{
    __shared__ int hist[256 * 65];
    __shared__ int seg[256];
    __shared__ int base[64];

    int bh = blockIdx.x;
    int tid = threadIdx.x;
    int w = tid >> 6, lane = tid & 63;

    for (int i = tid; i < 256 * 65; i += 256) hist[i] = 0;

    int myb[16];
    {   // coalesced bucket loads: 16 B/lane
        const int4* bp4 = (const int4*)(buckets + (size_t)bh * SEQ);
#pragma unroll
        for (int u4 = 0; u4 < 4; ++u4) {
            int4 bb = bp4[tid * 4 + u4];
            myb[u4*4+0] = bb.x; myb[u4*4+1] = bb.y;
            myb[u4*4+2] = bb.z; myb[u4*4+3] = bb.w;
        }
    }
    __syncthreads();
    int* hrow = &hist[tid * 65];
#pragma unroll
    for (int u = 0; u < 16; ++u) hrow[myb[u]] += 1;
    __syncthreads();

    {   // per-wave segment prefix: bucket = lane, tids [w*64, w*64+64)
        int run = 0;
        for (int tp = 0; tp < 64; ++tp) {
            int idx = (w * 64 + tp) * 65 + lane;
            int c0 = hist[idx];
            hist[idx] = run;
            run += c0;
        }
        seg[w * 64 + lane] = run;
    }
    __syncthreads();
    if (tid < 64) {   // cross-wave seg scan + bucket bases (wave 0)
        int s0 = seg[lane], s1 = seg[64 + lane], s2 = seg[128 + lane], s3 = seg[192 + lane];
        seg[lane] = 0; seg[64 + lane] = s0;
        seg[128 + lane] = s0 + s1; seg[192 + lane] = s0 + s1 + s2;
        int tot = s0 + s1 + s2 + s3;
        int x = tot;
#pragma unroll
        for (int d = 1; d < 64; d <<= 1) {
            int y = __shfl_up(x, d, 64);
            if (lane >= d) x += y;
        }
        base[lane] = x - tot;   // exclusive prefix over buckets
    }
    __syncthreads();

    int* op = st + (size_t)bh * SEQ;
#pragma unroll
    for (int u = 0; u < 16; ++u) {
        int bb = myb[u];
        int local = hrow[bb];
        hrow[bb] = local + 1;
        int pos = base[bb] + seg[w * 64 + bb] + local;
        op[pos] = tid * 16 + u;
    }
}

// ---------------------------------------------------------------------------
// Kernel 3: MFMA attention (unchanged from R9: split-bf16 3-MFMA products,
// Q frags in registers, P aliases K, 37 KB LDS -> 4 blocks/CU, token-major
// scatter epilogue, no atomics).
// ---------------------------------------------------------------------------
__global__ __launch_bounds__(256, 4) void lsh_attn_kernel(
    const float* __restrict__ qk, const float* __restrict__ v,
    const int* __restrict__ st, float* __restrict__ Obuf, float* __restrict__ Dbuf)
{
    __shared__ short Khi[64 * SB], Klo[64 * SB];   // double as Phi/Plo after dots
    __shared__ short Vhi[64 * SB], Vlo[64 * SB];   // transposed: [dim][key]
    __shared__ int   tk[64];

    short* Phi = Khi;
    short* Plo = Klo;

    int tid  = threadIdx.x;
    int lane = tid & 63;
    int w    = tid >> 6;          // wave id = query-strip / V key-group
    int quad = lane >> 4;
    int l15  = lane & 15;

    int bc = blockIdx.x;
    int b = bc >> 9, c = bc & (NCHUNK - 1);
    int cm = (c + NCHUNK - 1) & (NCHUNK - 1);

    const int*   stb = st + (size_t)b * (NHASH * SEQ);
    const float* qkb = qk + (size_t)b * SEQ * DIM;
    const float* vb  = v  + (size_t)b * SEQ * DIM;

    // ---- Q fragments in registers (both halves use the same Q) ----
    short8 qH[2], qL[2];
    {
        int qt = stb[c * 64 + 16 * w + l15];       // this lane's Q row token
        const float* qp = qkb + (size_t)qt * DIM + 8 * quad;
        float xs[8];
#pragma unroll
        for (int kb = 0; kb < 2; ++kb) {
            *(float4*)&xs[0] = *(const float4*)(qp + 32 * kb);
            *(float4*)&xs[4] = *(const float4*)(qp + 32 * kb + 4);
            split8_frag(xs, &qH[kb], &qL[kb]);
        }
    }
    // mask row-ids for this lane's C-fragment rows (quad*4+r), both halves
    int tqr[4];
#pragma unroll
    for (int r = 0; r < 4; ++r) tqr[r] = stb[c * 64 + 16 * w + quad * 4 + r];

    float   Dacc[4] = {0.f, 0.f, 0.f, 0.f};
    floatx4 oacc[4];
#pragma unroll
    for (int a = 0; a < 4; ++a) oacc[a] = (floatx4){0.f, 0.f, 0.f, 0.f};

    for (int half = 0; half < 2; ++half) {
        int ck = half ? cm : c;
        __syncthreads();              // prev-half P/V LDS reads complete

        {   // stage K (L2-normalized) split: 4 threads/row, 16 dims each
            int r = tid >> 2, s = tid & 3;
            int trow = stb[ck * 64 + r];
            if (s == 0) tk[r] = trow;
            const float4* k4 = (const float4*)(qkb + (size_t)trow * DIM + s * 16);
            float xs[16];
            *(float4*)&xs[0]  = k4[0];
            *(float4*)&xs[4]  = k4[1];
            *(float4*)&xs[8]  = k4[2];
            *(float4*)&xs[12] = k4[3];
            float ss = 0.f;
#pragma unroll
            for (int u = 0; u < 16; ++u) ss += xs[u] * xs[u];
            ss += __shfl_xor(ss, 1);
            ss += __shfl_xor(ss, 2);
            float sc = 1.0f / fmaxf(sqrtf(ss), 1e-12f);
#pragma unroll
            for (int u = 0; u < 16; ++u) xs[u] *= sc;
            split16_store(xs, &Khi[r * SB + s * 16], &Klo[r * SB + s * 16]);
        }
        {   // stage V TRANSPOSED split: thread = dim lane, keys w*16..w*16+15
            float xs[16];
#pragma unroll
            for (int u = 0; u < 16; ++u) {
                int trow = stb[ck * 64 + w * 16 + u];     // wave-uniform
                xs[u] = vb[(size_t)trow * DIM + lane];    // coalesced 256B row
            }
            split16_store(xs, &Vhi[lane * SB + w * 16], &Vlo[lane * SB + w * 16]);
        }
        __syncthreads();              // K, Vt, tk staged

        // dots: D = Q·K^T over 4 key-tiles, K=64 = 2 k-blocks, 3-term split
        floatx4 dt[4];
#pragma unroll
        for (int jt = 0; jt < 4; ++jt) dt[jt] = (floatx4){0.f, 0.f, 0.f, 0.f};
#pragma unroll
        for (int kb = 0; kb < 2; ++kb) {
#pragma unroll
            for (int jt = 0; jt < 4; ++jt) {
                short8 bH = *(const short8*)&Khi[(16 * jt + l15) * SB + kb * 32 + quad * 8];
                short8 bL = *(const short8*)&Klo[(16 * jt + l15) * SB + kb * 32 + quad * 8];
                dt[jt] = __builtin_amdgcn_mfma_f32_16x16x32_bf16(qH[kb], bH, dt[jt], 0, 0, 0);
                dt[jt] = __builtin_amdgcn_mfma_f32_16x16x32_bf16(qL[kb], bH, dt[jt], 0, 0, 0);
                dt[jt] = __builtin_amdgcn_mfma_f32_16x16x32_bf16(qH[kb], bL, dt[jt], 0, 0, 0);
            }
        }
        __syncthreads();              // all dots reads of K done -> P may overwrite

        // mask + exp (fp32) + wave-private P split-write + denominator partials
#pragma unroll
        for (int jt = 0; jt < 4; ++jt) {
            int tkc = tk[16 * jt + l15];
#pragma unroll
            for (int r = 0; r < 4; ++r) {
                float p = (tqr[r] == tkc) ? 0.f : __expf(dt[jt][r] * 0.125f);
                Dacc[r] += p;
                int idx = (16 * w + quad * 4 + r) * SB + 16 * jt + l15;
                Phi[idx] = (short)(__float_as_uint(p) >> 16);
                Plo[idx] = (short)(__float_as_uint(p - trunc_hi(p)) >> 16);
            }
        }

        // PV: O += P·V (A = own P strip -> no barrier; B = Vt)
#pragma unroll
        for (int kb = 0; kb < 2; ++kb) {
            short8 aH = *(const short8*)&Phi[(16 * w + l15) * SB + kb * 32 + quad * 8];
            short8 aL = *(const short8*)&Plo[(16 * w + l15) * SB + kb * 32 + quad * 8];
#pragma unroll
            for (int a = 0; a < 4; ++a) {
                short8 bH = *(const short8*)&Vhi[(16 * a + l15) * SB + kb * 32 + quad * 8];
                short8 bL = *(const short8*)&Vlo[(16 * a + l15) * SB + kb * 32 + quad * 8];
                oacc[a] = __builtin_amdgcn_mfma_f32_16x16x32_bf16(aH, bH, oacc[a], 0, 0, 0);
                oacc[a] = __builtin_amdgcn_mfma_f32_16x16x32_bf16(aL, bH, oacc[a], 0, 0, 0);
                oacc[a] = __builtin_amdgcn_mfma_f32_16x16x32_bf16(aH, bL, oacc[a], 0, 0, 0);
            }
        }
    }

    // epilogue: scatter to token-major rows O[(b*4096+t)*8 + h][64], h = c>>6.
    int h = c >> 6;
#pragma unroll
    for (int r = 0; r < 4; ++r) {
        int t = tqr[r];
        size_t rowb = ((size_t)(b * SEQ + t) * NHASH + h) * DIM;
#pragma unroll
        for (int a = 0; a < 4; ++a)
            Obuf[rowb + 16 * a + l15] = oacc[a][r];
    }
#pragma unroll
    for (int r = 0; r < 4; ++r) {
        float rs = Dacc[r];
        rs += __shfl_xor(rs, 1);
        rs += __shfl_xor(rs, 2);
        rs += __shfl_xor(rs, 4);
        rs += __shfl_xor(rs, 8);
        if (l15 == 0) Dbuf[(size_t)(b * SEQ + tqr[r]) * NHASH + h] = rs;
    }
}

// ---------------------------------------------------------------------------
// Kernel 4: out[b,t] = sum_h O[(b,t),h] / sum_h D[(b,t),h] -- fully
// streaming: per token 8x256 B contiguous O + 32 B D, all independent loads.
// ---------------------------------------------------------------------------
__global__ __launch_bounds__(256) void lsh_combine_tok(
    const float* __restrict__ Obuf, const float* __restrict__ Dbuf,
    float* __restrict__ out)
{
    int gid = blockIdx.x * 256 + threadIdx.x;   // (b*4096+t)*16 + d4
    int d4 = gid & 15;
    int bt = gid >> 4;

    const float4* op = (const float4*)Obuf + (size_t)bt * (NHASH * 16);
    const float*  dp = Dbuf + (size_t)bt * NHASH;

    float4 n = make_float4(0.f, 0.f, 0.f, 0.f);
    float den = 0.f;
#pragma unroll
    for (int h = 0; h < NHASH; ++h) {
        float4 o = op[h * 16 + d4];
        den += dp[h];
        n.x += o.x; n.y += o.y; n.z += o.z; n.w += o.w;
    }
    float invd = 1.0f / den;
    float4 r; r.x = n.x*invd; r.y = n.y*invd; r.z = n.z*invd; r.w = n.w*invd;
    ((float4*)out)[gid] = r;
}

extern "C" void kernel_launch(void* const* d_in, const int* in_sizes, int n_in,
                              void* d_out, int out_size, void* d_ws, size_t ws_size,
                              hipStream_t stream)
{
    const float* qk  = (const float*)d_in[0];
    const float* v   = (const float*)d_in[1];
    const float* rot = (const float*)d_in[2];
    float* out = (float*)d_out;

    char* w = (char*)d_ws;
    // workspace layout (140.5 MB):
    //   [0, 2MB)        buckets : int[16*8*4096]
    //   [2, 4MB)        st      : int[16*8*4096]
    //   [4MB, +134.2MB) Obuf    : fp32[16*4096*8*64]  (token-major, h inner)
    //   then            Dbuf    : fp32[16*4096*8]
    int*   buckets = (int*)(w);
    int*   st      = (int*)(w + 2097152);
    float* Obuf    = (float*)(w + 4194304);
    float* Dbuf    = (float*)(w + 4194304 + 134217728);

    lsh_hash_kernel<<<512, 256, 0, stream>>>(qk, rot, buckets);
    lsh_sort_kernel<<<128, 256, 0, stream>>>(buckets, st);
    lsh_attn_kernel<<<8192, 256, 0, stream>>>(qk, v, st, Obuf, Dbuf);
    lsh_combine_tok<<<4096, 256, 0, stream>>>(Obuf, Dbuf, out);
}

// Round 11
// 229.122 us; speedup vs baseline: 10.6601x; 1.0659x over previous
//
#include <hip/hip_runtime.h>

#define BATCH  16
#define SEQ    4096
#define DIM    64
#define NHASH  8
#define NCHUNK 512   // chunks per batch row (NHASH * SEQ / 64)
#define SB     72    // bf16 LDS row stride: 72*2=144 B, 16B-aligned for b128

typedef __attribute__((ext_vector_type(8))) short short8;   // 8 bf16 (4 VGPR)
typedef __attribute__((ext_vector_type(4))) float floatx4;  // MFMA C/D

__device__ __forceinline__ float trunc_hi(float a) {
    return __uint_as_float(__float_as_uint(a) & 0xffff0000u);
}
__device__ __forceinline__ unsigned pack_hi2(float a, float b) {
    return (__float_as_uint(a) >> 16) | (__float_as_uint(b) & 0xffff0000u);
}
// 16 fp32 -> 16 bf16 (truncation) stored as 2x uint4
__device__ __forceinline__ void hi16_store(const float* xs, short* dst) {
    unsigned hd[8];
#pragma unroll
    for (int u = 0; u < 8; ++u) hd[u] = pack_hi2(xs[2*u], xs[2*u + 1]);
    *(uint4*)(dst)     = make_uint4(hd[0], hd[1], hd[2], hd[3]);
    *(uint4*)(dst + 8) = make_uint4(hd[4], hd[5], hd[6], hd[7]);
}
// split 8 fp32 -> bf16 hi/lo short8 fragments in registers
__device__ __forceinline__ void split8_frag(const float* xs, short8* hi, short8* lo) {
    union { unsigned u[4]; short8 s; } H, L;
#pragma unroll
    for (int u = 0; u < 4; ++u) {
        float a = xs[2*u], b = xs[2*u + 1];
        H.u[u] = pack_hi2(a, b);
        L.u[u] = pack_hi2(a - trunc_hi(a), b - trunc_hi(b));
    }
    *hi = H.s; *lo = L.s;
}

// ---------------------------------------------------------------------------
// Kernel 1: LSH hashing (unchanged from R10: rot slice in LDS, broadcast
// ds_read_b128 + dense fp32 FMA, 2 tokens/thread, 2 h'/thread).
// ---------------------------------------------------------------------------
__global__ __launch_bounds__(256, 2) void lsh_hash_kernel(
    const float* __restrict__ qk, const float* __restrict__ rot,
    int* __restrict__ buckets)
{
    __shared__ float rs[64 * 128];     // [f][h'][i] = f*128 + h'*32 + i (32 KB)
    int tid = threadIdx.x;
    int tb   = blockIdx.x >> 1;        // 256-token tile
    int hsel = blockIdx.x & 1;         // h half: h = hsel*4 + h'

    {   // stage rot slice: 2048 float4, 8 per thread, coalesced
        const float4* rg = (const float4*)rot;
#pragma unroll
        for (int j = 0; j < 8; ++j) {
            int idx4 = j * 256 + tid;
            int f = idx4 >> 5, r4 = idx4 & 31;
            ((float4*)rs)[idx4] = rg[f * 64 + hsel * 32 + r4];
        }
    }
    __syncthreads();

    int tt = tid & 127;
    int hh = tid >> 7;                 // 0/1, wave-uniform
    int gid0 = tb * 256 + tt;
    int gid1 = gid0 + 128;
    const float* q0 = qk + (size_t)gid0 * DIM;
    const float* q1 = qk + (size_t)gid1 * DIM;

#pragma unroll
    for (int h0 = 0; h0 < 2; ++h0) {
        int hp = hh * 2 + h0;
        const float* rbase = rs + hp * 32;
        float a0[32], a1[32];
#pragma unroll
        for (int i = 0; i < 32; ++i) { a0[i] = 0.f; a1[i] = 0.f; }
#pragma unroll 1
        for (int ft = 0; ft < 8; ++ft) {
            float qa[8], qb[8];
            *(float4*)&qa[0] = *(const float4*)(q0 + ft * 8);
            *(float4*)&qa[4] = *(const float4*)(q0 + ft * 8 + 4);
            *(float4*)&qb[0] = *(const float4*)(q1 + ft * 8);
            *(float4*)&qb[4] = *(const float4*)(q1 + ft * 8 + 4);
#pragma unroll
            for (int f8 = 0; f8 < 8; ++f8) {
                const float* rp = rbase + (ft * 8 + f8) * 128;
                float x = qa[f8], y = qb[f8];
#pragma unroll
                for (int i = 0; i < 32; ++i) {
                    float r = rp[i];
                    a0[i] = fmaf(x, r, a0[i]);
                    a1[i] = fmaf(y, r, a1[i]);
                }
            }
        }
        int h = hsel * 4 + hp;
        {
            float best = a0[0]; int bi = 0;
#pragma unroll
            for (int i = 1; i < 32; ++i) { if (a0[i] > best) { best = a0[i]; bi = i; } }
#pragma unroll
            for (int i = 0; i < 32; ++i) { float nv = -a0[i]; if (nv > best) { best = nv; bi = i + 32; } }
            int b = gid0 >> 12, t = gid0 & 4095;
            buckets[((size_t)b * NHASH + h) * SEQ + t] = bi;
        }
        {
            float best = a1[0]; int bi = 0;
#pragma unroll
            for (int i = 1; i < 32; ++i) { if (a1[i] > best) { best = a1[i]; bi = i; } }
#pragma unroll
            for (int i = 0; i < 32; ++i) { float nv = -a1[i]; if (nv > best) { best = nv; bi = i + 32; } }
            int b = gid1 >> 12, t = gid1 & 4095;
            buckets[((size_t)b * NHASH + h) * SEQ + t] = bi;
        }
    }
}

// ---------------------------------------------------------------------------
// Kernel 2: stable counting sort per (b,h), 4-wave (unchanged from R10).
// ---------------------------------------------------------------------------
__global__ __launch_bounds__(256) void lsh_sort_kernel(
    const int* __restrict__ buckets, int* __restrict__ st)
{
    __shared__ int hist[256 * 65];
    __shared__ int seg[256];
    __shared__ int base[64];

    int bh = blockIdx.x;
    int tid = threadIdx.x;
    int w = tid >> 6, lane = tid & 63;

    for (int i = tid; i < 256 * 65; i += 256) hist[i] = 0;

    int myb[16];
    {
        const int4* bp4 = (const int4*)(buckets + (size_t)bh * SEQ);
#pragma unroll
        for (int u4 = 0; u4 < 4; ++u4) {
            int4 bb = bp4[tid * 4 + u4];
            myb[u4*4+0] = bb.x; myb[u4*4+1] = bb.y;
            myb[u4*4+2] = bb.z; myb[u4*4+3] = bb.w;
        }
    }
    __syncthreads();
    int* hrow = &hist[tid * 65];
#pragma unroll
    for (int u = 0; u < 16; ++u) hrow[myb[u]] += 1;
    __syncthreads();

    {
        int run = 0;
        for (int tp = 0; tp < 64; ++tp) {
            int idx = (w * 64 + tp) * 65 + lane;
            int c0 = hist[idx];
            hist[idx] = run;
            run += c0;
        }
        seg[w * 64 + lane] = run;
    }
    __syncthreads();
    if (tid < 64) {
        int s0 = seg[lane], s1 = seg[64 + lane], s2 = seg[128 + lane], s3 = seg[192 + lane];
        seg[lane] = 0; seg[64 + lane] = s0;
        seg[128 + lane] = s0 + s1; seg[192 + lane] = s0 + s1 + s2;
        int tot = s0 + s1 + s2 + s3;
        int x = tot;
#pragma unroll
        for (int d = 1; d < 64; d <<= 1) {
            int y = __shfl_up(x, d, 64);
            if (lane >= d) x += y;
        }
        base[lane] = x - tot;
    }
    __syncthreads();

    int* op = st + (size_t)bh * SEQ;
#pragma unroll
    for (int u = 0; u < 16; ++u) {
        int bb = myb[u];
        int local = hrow[bb];
        hrow[bb] = local + 1;
        int pos = base[bb] + seg[w * 64 + bb] + local;
        op[pos] = tid * 16 + u;
    }
}

// ---------------------------------------------------------------------------
// Kernel 3: MFMA attention, LDS-pipe + footprint trim (R10 counters: LDS
// pipe ~65% busy = bottleneck; 37.4 KB = 4 blocks/CU cap). Changes:
//  - dots drops the K-lo term: dt = (qH+qL)*kH = q*kH. err = q*k_lo ~1e-3
//    on dots, *0.125 in exponent -> p rel err ~1e-4 (negligible). Saves
//    8 MFMAs + 8 B-reads + Klo staging per half.
//  - V stored hi-only (PV = PH*VH + PL*VH): out err = weighted mean of v_lo
//    (zero-mean, ~1e-4 rms, tail ~6e-4). Kills Vlo tile: LDS 37.4 -> 27.9 KB
//    -> 5 blocks/CU (20 waves). Saves 8 B-reads + 8 MFMAs per half.
//  - P keeps FULL hi+lo precision (Plo in the tile Klo used to occupy).
// Per half: LDS insts 76->56, MFMA 48->32. absmax budget: ~1e-3 (existing)
// + ~6e-4 (V-hi) + ~1e-4 (dots) -- expect <=2e-3 vs 3.6e-3 threshold.
// ---------------------------------------------------------------------------
__global__ __launch_bounds__(256, 5) void lsh_attn_kernel(
    const float* __restrict__ qk, const float* __restrict__ v,
    const int* __restrict__ st, float* __restrict__ Obuf, float* __restrict__ Dbuf)
{
    __shared__ short Khi[64 * SB];     // staged K-hi; doubles as Phi after dots
    __shared__ short Psp[64 * SB];     // Plo tile (written after dots only)
    __shared__ short Vhi[64 * SB];     // transposed: [dim][key], hi only
    __shared__ int   tk[64];

    short* Phi = Khi;
    short* Plo = Psp;

    int tid  = threadIdx.x;
    int lane = tid & 63;
    int w    = tid >> 6;          // wave id = query-strip / V key-group
    int quad = lane >> 4;
    int l15  = lane & 15;

    int bc = blockIdx.x;
    int b = bc >> 9, c = bc & (NCHUNK - 1);
    int cm = (c + NCHUNK - 1) & (NCHUNK - 1);

    const int*   stb = st + (size_t)b * (NHASH * SEQ);
    const float* qkb = qk + (size_t)b * SEQ * DIM;
    const float* vb  = v  + (size_t)b * SEQ * DIM;

    // ---- Q fragments in registers (both halves use the same Q) ----
    short8 qH[2], qL[2];
    {
        int qt = stb[c * 64 + 16 * w + l15];       // this lane's Q row token
        const float* qp = qkb + (size_t)qt * DIM + 8 * quad;
        float xs[8];
#pragma unroll
        for (int kb = 0; kb < 2; ++kb) {
            *(float4*)&xs[0] = *(const float4*)(qp + 32 * kb);
            *(float4*)&xs[4] = *(const float4*)(qp + 32 * kb + 4);
            split8_frag(xs, &qH[kb], &qL[kb]);
        }
    }
    // mask row-ids for this lane's C-fragment rows (quad*4+r), both halves
    int tqr[4];
#pragma unroll
    for (int r = 0; r < 4; ++r) tqr[r] = stb[c * 64 + 16 * w + quad * 4 + r];

    float   Dacc[4] = {0.f, 0.f, 0.f, 0.f};
    floatx4 oacc[4];
#pragma unroll
    for (int a = 0; a < 4; ++a) oacc[a] = (floatx4){0.f, 0.f, 0.f, 0.f};

    for (int half = 0; half < 2; ++half) {
        int ck = half ? cm : c;
        __syncthreads();              // prev-half P/V LDS reads complete

        {   // stage K (L2-normalized, hi-only): 4 threads/row, 16 dims each
            int r = tid >> 2, s = tid & 3;
            int trow = stb[ck * 64 + r];
            if (s == 0) tk[r] = trow;
            const float4* k4 = (const float4*)(qkb + (size_t)trow * DIM + s * 16);
            float xs[16];
            *(float4*)&xs[0]  = k4[0];
            *(float4*)&xs[4]  = k4[1];
            *(float4*)&xs[8]  = k4[2];
            *(float4*)&xs[12] = k4[3];
            float ss = 0.f;
#pragma unroll
            for (int u = 0; u < 16; ++u) ss += xs[u] * xs[u];
            ss += __shfl_xor(ss, 1);
            ss += __shfl_xor(ss, 2);
            float sc = 1.0f / fmaxf(sqrtf(ss), 1e-12f);
#pragma unroll
            for (int u = 0; u < 16; ++u) xs[u] *= sc;
            hi16_store(xs, &Khi[r * SB + s * 16]);
        }
        {   // stage V TRANSPOSED (hi-only): thread = dim lane, keys w*16..+15
            float xs[16];
#pragma unroll
            for (int u = 0; u < 16; ++u) {
                int trow = stb[ck * 64 + w * 16 + u];     // wave-uniform
                xs[u] = vb[(size_t)trow * DIM + lane];    // coalesced 256B row
            }
            hi16_store(xs, &Vhi[lane * SB + w * 16]);
        }
        __syncthreads();              // K, Vt, tk staged

        // dots: dt = q · K_hi^T  (2-term split: (qH+qL)*kH)
        floatx4 dt[4];
#pragma unroll
        for (int jt = 0; jt < 4; ++jt) dt[jt] = (floatx4){0.f, 0.f, 0.f, 0.f};
#pragma unroll
        for (int kb = 0; kb < 2; ++kb) {
#pragma unroll
            for (int jt = 0; jt < 4; ++jt) {
                short8 bH = *(const short8*)&Khi[(16 * jt + l15) * SB + kb * 32 + quad * 8];
                dt[jt] = __builtin_amdgcn_mfma_f32_16x16x32_bf16(qH[kb], bH, dt[jt], 0, 0, 0);
                dt[jt] = __builtin_amdgcn_mfma_f32_16x16x32_bf16(qL[kb], bH, dt[jt], 0, 0, 0);
            }
        }
        __syncthreads();              // all dots reads of K done -> P may overwrite

        // mask + exp (fp32) + wave-private P split-write + denominator partials
#pragma unroll
        for (int jt = 0; jt < 4; ++jt) {
            int tkc = tk[16 * jt + l15];
#pragma unroll
            for (int r = 0; r < 4; ++r) {
                float p = (tqr[r] == tkc) ? 0.f : __expf(dt[jt][r] * 0.125f);
                Dacc[r] += p;
                int idx = (16 * w + quad * 4 + r) * SB + 16 * jt + l15;
                Phi[idx] = (short)(__float_as_uint(p) >> 16);
                Plo[idx] = (short)(__float_as_uint(p - trunc_hi(p)) >> 16);
            }
        }

        // PV: O += P·V_hi (A = own P strip -> no barrier; B = Vt hi)
#pragma unroll
        for (int kb = 0; kb < 2; ++kb) {
            short8 aH = *(const short8*)&Phi[(16 * w + l15) * SB + kb * 32 + quad * 8];
            short8 aL = *(const short8*)&Plo[(16 * w + l15) * SB + kb * 32 + quad * 8];
#pragma unroll
            for (int a = 0; a < 4; ++a) {
                short8 bH = *(const short8*)&Vhi[(16 * a + l15) * SB + kb * 32 + quad * 8];
                oacc[a] = __builtin_amdgcn_mfma_f32_16x16x32_bf16(aH, bH, oacc[a], 0, 0, 0);
                oacc[a] = __builtin_amdgcn_mfma_f32_16x16x32_bf16(aL, bH, oacc[a], 0, 0, 0);
            }
        }
    }

    // epilogue: scatter to token-major rows O[(b*4096+t)*8 + h][64], h = c>>6.
    int h = c >> 6;
#pragma unroll
    for (int r = 0; r < 4; ++r) {
        int t = tqr[r];
        size_t rowb = ((size_t)(b * SEQ + t) * NHASH + h) * DIM;
#pragma unroll
        for (int a = 0; a < 4; ++a)
            Obuf[rowb + 16 * a + l15] = oacc[a][r];
    }
#pragma unroll
    for (int r = 0; r < 4; ++r) {
        float rs = Dacc[r];
        rs += __shfl_xor(rs, 1);
        rs += __shfl_xor(rs, 2);
        rs += __shfl_xor(rs, 4);
        rs += __shfl_xor(rs, 8);
        if (l15 == 0) Dbuf[(size_t)(b * SEQ + tqr[r]) * NHASH + h] = rs;
    }
}

// ---------------------------------------------------------------------------
// Kernel 4: out[b,t] = sum_h O[(b,t),h] / sum_h D[(b,t),h] -- streaming.
// ---------------------------------------------------------------------------
__global__ __launch_bounds__(256) void lsh_combine_tok(
    const float* __restrict__ Obuf, const float* __restrict__ Dbuf,
    float* __restrict__ out)
{
    int gid = blockIdx.x * 256 + threadIdx.x;   // (b*4096+t)*16 + d4
    int d4 = gid & 15;
    int bt = gid >> 4;

    const float4* op = (const float4*)Obuf + (size_t)bt * (NHASH * 16);
    const float*  dp = Dbuf + (size_t)bt * NHASH;

    float4 n = make_float4(0.f, 0.f, 0.f, 0.f);
    float den = 0.f;
#pragma unroll
    for (int h = 0; h < NHASH; ++h) {
        float4 o = op[h * 16 + d4];
        den += dp[h];
        n.x += o.x; n.y += o.y; n.z += o.z; n.w += o.w;
    }
    float invd = 1.0f / den;
    float4 r; r.x = n.x*invd; r.y = n.y*invd; r.z = n.z*invd; r.w = n.w*invd;
    ((float4*)out)[gid] = r;
}

extern "C" void kernel_launch(void* const* d_in, const int* in_sizes, int n_in,
                              void* d_out, int out_size, void* d_ws, size_t ws_size,
                              hipStream_t stream)
{
    const float* qk  = (const float*)d_in[0];
    const float* v   = (const float*)d_in[1];
    const float* rot = (const float*)d_in[2];
    float* out = (float*)d_out;

    char* w = (char*)d_ws;
    // workspace layout (140.5 MB):
    //   [0, 2MB)        buckets : int[16*8*4096]
    //   [2, 4MB)        st      : int[16*8*4096]
    //   [4MB, +134.2MB) Obuf    : fp32[16*4096*8*64]  (token-major, h inner)
    //   then            Dbuf    : fp32[16*4096*8]
    int*   buckets = (int*)(w);
    int*   st      = (int*)(w + 2097152);
    float* Obuf    = (float*)(w + 4194304);
    float* Dbuf    = (float*)(w + 4194304 + 134217728);

    lsh_hash_kernel<<<512, 256, 0, stream>>>(qk, rot, buckets);
    lsh_sort_kernel<<<128, 256, 0, stream>>>(buckets, st);
    lsh_attn_kernel<<<8192, 256, 0, stream>>>(qk, v, st, Obuf, Dbuf);
    lsh_combine_tok<<<4096, 256, 0, stream>>>(Obuf, Dbuf, out);
}